// Round 5
// baseline (28779.471 us; speedup 1.0000x reference)
//
#include <hip/hip_runtime.h>

#define DEVINL __device__ __forceinline__

DEVINL void fma4(float4& a, const float4 w, const float x) {
    a.x += w.x * x; a.y += w.y * x; a.z += w.z * x; a.w += w.w * x;
}

// ===========================================================================
// CSR build: counting sort of edges by dst.
// ===========================================================================
__global__ __launch_bounds__(256) void hist_kernel(const int* __restrict__ d,
                                                   int* __restrict__ counts, int n) {
    for (int i = blockIdx.x * 256 + threadIdx.x; i < n; i += gridDim.x * 256)
        atomicAdd(&counts[d[i]], 1);
}

__global__ __launch_bounds__(1024) void scan_block(const int* __restrict__ in,
                                                   int* __restrict__ out,
                                                   int* __restrict__ bsums, int n) {
    __shared__ int buf[2][1024];
    const int t = threadIdx.x;
    const int i = blockIdx.x * 1024 + t;
    const int v = (i < n) ? in[i] : 0;
    int cur = 0;
    buf[0][t] = v;
    __syncthreads();
    #pragma unroll
    for (int s = 1; s < 1024; s <<= 1) {
        int x = buf[cur][t];
        if (t >= s) x += buf[cur][t - s];
        buf[cur ^ 1][t] = x;
        cur ^= 1;
        __syncthreads();
    }
    if (i < n) out[i] = buf[cur][t] - v;            // exclusive
    if (t == 1023) bsums[blockIdx.x] = buf[cur][t]; // block total
}

__global__ void scan_small(int* __restrict__ bs, int nb) {
    if (blockIdx.x == 0 && threadIdx.x == 0) {
        int acc = 0;
        for (int i = 0; i < nb; i++) { int v = bs[i]; bs[i] = acc; acc += v; }
    }
}

__global__ __launch_bounds__(1024) void add_offsets(int* __restrict__ out,
                                                    const int* __restrict__ bs, int n) {
    int i = blockIdx.x * 1024 + threadIdx.x;
    if (i < n) out[i] += bs[blockIdx.x];
}

__global__ __launch_bounds__(256) void scatter_kernel(const int* __restrict__ d,
                                                      int* __restrict__ cursor,
                                                      int* __restrict__ eidS,
                                                      int* __restrict__ dS, int n) {
    for (int i = blockIdx.x * 256 + threadIdx.x; i < n; i += gridDim.x * 256) {
        int dd = d[i];
        int pos = atomicAdd(&cursor[dd], 1);
        eidS[pos] = i;
        dS[pos] = dd;
    }
}

// ===========================================================================
// Edge kernel (dst-sorted, LDS-staged):
//   256 threads / 128 edges per block; 2 threads per edge split K in half.
//   Phase 1: stage 128 h[src] rows into LDS (burst: every line fetched once,
//            enforced by the barrier) -> consume (FMA vs W tile in LDS).
//   Phase 2: same for 128 efeat rows (same union buffer).
//   Phase 3: merge K-half partials through LDS, relu.
//   Phase 4: segmented reduction by (sorted) dst, ~1 atomic per segment.
// Odd LDS strides => 2-way bank aliasing only (free). W reads are
// wave-uniform broadcasts. Grid sized exactly: nEdges % 128 == 0.
// ===========================================================================
template<int FIN, int FINP, int FOUT, int FOUTP, int MS>
__global__ __launch_bounds__(256) void edge_kernel(
    const float* __restrict__ h,
    const float* __restrict__ efeats,
    const int* __restrict__ src,
    const int* __restrict__ eidS,
    const int* __restrict__ dS,
    const float* __restrict__ W,
    const float* __restrict__ b,
    float* __restrict__ agg)
{
    constexpr int K    = FINP + 64;     // padded input length
    constexpr int F4   = FOUTP / 4;
    constexpr int STH  = FINP + 1;      // h stage stride (odd)
    constexpr int STE  = 65;            // e stage stride (odd)
    constexpr int SBUF = 128 * STE;     // floats; covers h-stage and msg too
    static_assert(128 * STH <= SBUF && 128 * MS + 64 <= SBUF, "sbuf too small");

    __shared__ float4 Wl[K * F4];
    __shared__ float  sbuf[SBUF];       // union: staged rows / msg+merge
    __shared__ float  bl[FOUTP];
    __shared__ int    eidL[128], sIdxL[128], dseg[128];

    const int tid = threadIdx.x;

    // ---- stage W: rows [0,FIN)=h-part, [FIN,FINP)=0, [FINP,FINP+64)=e-part
    for (int idx = tid; idx < K * FOUTP; idx += 256) {
        int k = idx / FOUTP;
        int j = idx - k * FOUTP;
        float v = 0.f;
        if (j < FOUT) {
            if (k < FIN)        v = W[k * FOUT + j];
            else if (k >= FINP) v = W[(FIN + (k - FINP)) * FOUT + j];
        }
        reinterpret_cast<float*>(Wl)[idx] = v;
    }
    if (tid < FOUTP) bl[tid] = (tid < FOUT) ? b[tid] : 0.f;
    if (tid < 128) {
        int p = blockIdx.x * 128 + tid;
        int e = eidS[p];
        eidL[tid]  = e;
        dseg[tid]  = dS[p];
        sIdxL[tid] = src[e];
    }
    __syncthreads();

    const int r  = tid & 127;   // edge slot in block
    const int kh = tid >> 7;    // K-half (0 or 1)

    float4 acc[F4];
    #pragma unroll
    for (int j4 = 0; j4 < F4; j4++)
        acc[j4] = (kh == 0) ? reinterpret_cast<float4*>(bl)[j4] : float4{0.f, 0.f, 0.f, 0.f};

    // ---- phase 1a: stage h rows (burst; barrier enforces completion) ----
    {
        constexpr int CH = FINP / 4;
        for (int i = tid; i < 128 * CH; i += 256) {
            int row = i / CH, c4 = i - row * CH;
            float4 v = *reinterpret_cast<const float4*>(h + (long long)sIdxL[row] * FINP + c4 * 4);
            float* d = &sbuf[row * STH + c4 * 4];
            d[0] = v.x; d[1] = v.y; d[2] = v.z; d[3] = v.w;
        }
    }
    __syncthreads();
    // ---- phase 1b: consume h (each thread: its K-half) ----
    {
        constexpr int KH2 = FINP / 2;
        const float* xrow = &sbuf[r * STH + kh * KH2];
        #pragma unroll
        for (int k = 0; k < KH2; k++) {
            float xk = xrow[k];
            const float4* wrow = &Wl[(kh * KH2 + k) * F4];
            #pragma unroll
            for (int j4 = 0; j4 < F4; j4++) fma4(acc[j4], wrow[j4], xk);
        }
    }
    __syncthreads();
    // ---- phase 2a: stage e rows ----
    for (int i = tid; i < 128 * 16; i += 256) {
        int row = i >> 4, c4 = i & 15;
        float4 v = *reinterpret_cast<const float4*>(efeats + (long long)eidL[row] * 64 + c4 * 4);
        float* d = &sbuf[row * STE + c4 * 4];
        d[0] = v.x; d[1] = v.y; d[2] = v.z; d[3] = v.w;
    }
    __syncthreads();
    // ---- phase 2b: consume e ----
    {
        const float* xrow = &sbuf[r * STE + kh * 32];
        #pragma unroll
        for (int k = 0; k < 32; k++) {
            float xk = xrow[k];
            const float4* wrow = &Wl[(FINP + kh * 32 + k) * F4];
            #pragma unroll
            for (int j4 = 0; j4 < F4; j4++) fma4(acc[j4], wrow[j4], xk);
        }
    }
    __syncthreads();
    // ---- phase 3: merge K-half partials, relu ----
    if (kh == 1) {
        #pragma unroll
        for (int j4 = 0; j4 < F4; j4++) {
            float4 a = acc[j4];
            float* d = &sbuf[r * MS + 4 * j4];
            if (4 * j4 + 0 < FOUT) d[0] = a.x;
            if (4 * j4 + 1 < FOUT) d[1] = a.y;
            if (4 * j4 + 2 < FOUT) d[2] = a.z;
            if (4 * j4 + 3 < FOUT) d[3] = a.w;
        }
    }
    __syncthreads();
    if (kh == 0) {
        #pragma unroll
        for (int j4 = 0; j4 < F4; j4++) {
            float4 a = acc[j4];
            float* d = &sbuf[r * MS + 4 * j4];
            if (4 * j4 + 0 < FOUT) d[0] = fmaxf(a.x + d[0], 0.f);
            if (4 * j4 + 1 < FOUT) d[1] = fmaxf(a.y + d[1], 0.f);
            if (4 * j4 + 2 < FOUT) d[2] = fmaxf(a.z + d[2], 0.f);
            if (4 * j4 + 3 < FOUT) d[3] = fmaxf(a.w + d[3], 0.f);
        }
    }
    __syncthreads();
    // ---- phase 4: segmented reduce (4 waves x 32 rows; lane = feature) ----
    const int lane = tid & 63;
    const int wv   = tid >> 6;
    for (int r0 = wv * 32; r0 < wv * 32 + 32; ++r0) {
        int dr = dseg[r0];
        if (r0 > 0 && dseg[r0 - 1] == dr) continue;   // not a segment start
        float s = 0.f;
        int rr = r0;
        while (true) {
            s += sbuf[rr * MS + lane];
            ++rr;
            if (rr >= 128 || dseg[rr] != dr) break;
        }
        if (lane < FOUT) atomicAdd(agg + (long long)dr * FOUT + lane, s);
    }
}

// ===========================================================================
// Node kernel: out = relu(cat(h, agg) @ W + b), one thread per node.
// ===========================================================================
template<int FH, int FHP, int FAGG, int FOUT, int FOUTP>
__global__ __launch_bounds__(256) void node_kernel(
    const float* __restrict__ h,
    const float* __restrict__ agg,
    const float* __restrict__ W,
    const float* __restrict__ b,
    float* __restrict__ out,
    int nNodes)
{
    constexpr int K  = FH + FAGG;
    constexpr int F4 = FOUTP / 4;

    __shared__ float4 Wl[K * F4];
    __shared__ float4 bl[F4];

    const int tid = threadIdx.x;
    for (int idx = tid; idx < K * FOUTP; idx += 256) {
        int k = idx / FOUTP;
        int j = idx - k * FOUTP;
        reinterpret_cast<float*>(Wl)[idx] = (j < FOUT) ? W[k * FOUT + j] : 0.f;
    }
    for (int idx = tid; idx < FOUTP; idx += 256)
        reinterpret_cast<float*>(bl)[idx] = (idx < FOUT) ? b[idx] : 0.f;
    __syncthreads();

    const int n = blockIdx.x * 256 + tid;
    if (n >= nNodes) return;

    float4 acc[F4];
    #pragma unroll
    for (int j4 = 0; j4 < F4; j4++) acc[j4] = bl[j4];

    const float* hrow = h + (long long)n * FHP;
    for (int k = 0; k < FH; k++) {
        float xk = hrow[k];
        const float4* wrow = &Wl[k * F4];
        #pragma unroll
        for (int j4 = 0; j4 < F4; j4++) fma4(acc[j4], wrow[j4], xk);
    }
    const float* arow = agg + (long long)n * FAGG;
    for (int k = 0; k < FAGG; k++) {
        float xk = arow[k];
        const float4* wrow = &Wl[(FH + k) * F4];
        #pragma unroll
        for (int j4 = 0; j4 < F4; j4++) fma4(acc[j4], wrow[j4], xk);
    }

    float4* orow = reinterpret_cast<float4*>(out + (long long)n * FOUTP);
    #pragma unroll
    for (int j4 = 0; j4 < F4; j4++) {
        float4 a = acc[j4];
        a.x = fmaxf(a.x, 0.f); a.y = fmaxf(a.y, 0.f);
        a.z = fmaxf(a.z, 0.f); a.w = fmaxf(a.w, 0.f);
        orow[j4] = a;
    }
}

extern "C" void kernel_launch(void* const* d_in, const int* in_sizes, int n_in,
                              void* d_out, int out_size, void* d_ws, size_t ws_size,
                              hipStream_t stream)
{
    const float* nfeats = (const float*)d_in[0];
    const float* efeats = (const float*)d_in[1];
    const int*   src    = (const int*)d_in[2];
    const int*   dst    = (const int*)d_in[3];
    const float* Wm1 = (const float*)d_in[4],  *bm1 = (const float*)d_in[5];
    const float* Wa1 = (const float*)d_in[6],  *ba1 = (const float*)d_in[7];
    const float* Wm2 = (const float*)d_in[8],  *bm2 = (const float*)d_in[9];
    const float* Wa2 = (const float*)d_in[10], *ba2 = (const float*)d_in[11];
    const float* Wm3 = (const float*)d_in[12], *bm3 = (const float*)d_in[13];
    const float* Wa3 = (const float*)d_in[14], *ba3 = (const float*)d_in[15];
    float* out = (float*)d_out;

    constexpr int N = 100000;
    constexpr int E = 3200000;                      // divisible by 128
    constexpr int SCAN_BLOCKS = (N + 1023) / 1024;  // 98

    float* ws   = (float*)d_ws;
    float* h1   = ws;                            // N x 52
    float* h2   = h1 + (size_t)N * 52;           // N x 28
    float* agg  = h2 + (size_t)N * 28;           // N x 52
    int* counts = (int*)(agg + (size_t)N * 52);  // N
    int* cursor = counts + N;                    // N
    int* bsums  = cursor + N;                    // 128
    int* eidS   = bsums + 128;                   // E
    int* dS     = eidS + E;                      // E

    // ---- CSR build (counting sort by dst) ----
    hipMemsetAsync(counts, 0, (size_t)N * sizeof(int), stream);
    hist_kernel<<<2048, 256, 0, stream>>>(dst, counts, E);
    scan_block<<<SCAN_BLOCKS, 1024, 0, stream>>>(counts, cursor, bsums, N);
    scan_small<<<1, 64, 0, stream>>>(bsums, SCAN_BLOCKS);
    add_offsets<<<SCAN_BLOCKS, 1024, 0, stream>>>(cursor, bsums, N);
    scatter_kernel<<<2048, 256, 0, stream>>>(dst, cursor, eidS, dS, E);

    const int EB = E / 128;          // 128 edges per block
    const int NB = (N + 255) / 256;

    // ---- layer 1 ----  edge: 64(+64) -> 50 (MS=51); node: 64+50 -> 50
    hipMemsetAsync(agg, 0, (size_t)N * 52 * sizeof(float), stream);
    edge_kernel<64, 64, 50, 52, 51><<<EB, 256, 0, stream>>>(nfeats, efeats, src, eidS, dS, Wm1, bm1, agg);
    node_kernel<64, 64, 50, 50, 52><<<NB, 256, 0, stream>>>(nfeats, agg, Wa1, ba1, h1, N);

    // ---- layer 2 ----  edge: 50(+64) -> 25 (MS=25); node: 50+25 -> 25
    hipMemsetAsync(agg, 0, (size_t)N * 52 * sizeof(float), stream);
    edge_kernel<50, 52, 25, 28, 25><<<EB, 256, 0, stream>>>(h1, efeats, src, eidS, dS, Wm2, bm2, agg);
    node_kernel<50, 52, 25, 25, 28><<<NB, 256, 0, stream>>>(h1, agg, Wa2, ba2, h2, N);

    // ---- layer 3 ----  edge: 25(+64) -> 32 (MS=33); node: 25+32 -> 32
    hipMemsetAsync(agg, 0, (size_t)N * 52 * sizeof(float), stream);
    edge_kernel<25, 28, 32, 32, 33><<<EB, 256, 0, stream>>>(h2, efeats, src, eidS, dS, Wm3, bm3, agg);
    node_kernel<25, 28, 32, 32, 32><<<NB, 256, 0, stream>>>(h2, agg, Wa3, ba3, out, N);
}

// Round 6
// 2912.620 us; speedup vs baseline: 9.8810x; 9.8810x over previous
//
#include <hip/hip_runtime.h>

#define DEVINL __device__ __forceinline__

DEVINL void fma4(float4& a, const float4 w, const float x) {
    a.x += w.x * x; a.y += w.y * x; a.z += w.z * x; a.w += w.w * x;
}

// ===========================================================================
// CSR build: counting sort of edges by dst.
// ===========================================================================
__global__ __launch_bounds__(256) void hist_kernel(const int* __restrict__ d,
                                                   int* __restrict__ counts, int n) {
    for (int i = blockIdx.x * 256 + threadIdx.x; i < n; i += gridDim.x * 256)
        atomicAdd(&counts[d[i]], 1);
}

__global__ __launch_bounds__(1024) void scan_block(const int* __restrict__ in,
                                                   int* __restrict__ out,
                                                   int* __restrict__ bsums, int n) {
    __shared__ int buf[2][1024];
    const int t = threadIdx.x;
    const int i = blockIdx.x * 1024 + t;
    const int v = (i < n) ? in[i] : 0;
    int cur = 0;
    buf[0][t] = v;
    __syncthreads();
    #pragma unroll
    for (int s = 1; s < 1024; s <<= 1) {
        int x = buf[cur][t];
        if (t >= s) x += buf[cur][t - s];
        buf[cur ^ 1][t] = x;
        cur ^= 1;
        __syncthreads();
    }
    if (i < n) out[i] = buf[cur][t] - v;            // exclusive
    if (t == 1023) bsums[blockIdx.x] = buf[cur][t]; // block total
}

__global__ void scan_small(int* __restrict__ bs, int nb) {
    if (blockIdx.x == 0 && threadIdx.x == 0) {
        int acc = 0;
        for (int i = 0; i < nb; i++) { int v = bs[i]; bs[i] = acc; acc += v; }
    }
}

__global__ __launch_bounds__(1024) void add_offsets(int* __restrict__ out,
                                                    const int* __restrict__ bs, int n) {
    int i = blockIdx.x * 1024 + threadIdx.x;
    if (i < n) out[i] += bs[blockIdx.x];
}

__global__ __launch_bounds__(256) void scatter_kernel(const int* __restrict__ d,
                                                      int* __restrict__ cursor,
                                                      int* __restrict__ eidS,
                                                      int* __restrict__ dS, int n) {
    for (int i = blockIdx.x * 256 + threadIdx.x; i < n; i += gridDim.x * 256) {
        int dd = d[i];
        int pos = atomicAdd(&cursor[dd], 1);
        eidS[pos] = i;
        dS[pos] = dd;
    }
}

// ===========================================================================
// Edge kernel (dst-sorted, chunk-staged, 2 edges/thread):
//   256 threads handle 512 edges/block. Thread t owns edges p0=blk*512+t and
//   p1=p0+256, accumulating BOTH full GEMVs (one W-row LDS read feeds 8 FMAs).
//   The gathered input rows (h[src], efeat) are staged into thread-private
//   LDS slots in 16-dword chunks: 4 back-to-back dwordx4 per row per chunk
//   (every cache line fetched exactly once, enforced by the post-stage
//   barrier), then consumed as scalar LDS reads against the LDS W tile.
//   Consume loops have runtime trip counts + unroll 1 => no full-unroll, no
//   VGPR spill (round-5 failure mode).
//   Epilogue: 4 batches of 128 messages -> LDS -> segmented reduce by sorted
//   dst -> ~1 atomic per (segment, feature).
// ST=17 (odd) => 2-way bank alias on stage/consume = free.
// Grid sized exactly: nEdges % 512 == 0.
// ===========================================================================
template<int FIN, int FINP, int FOUT, int FOUTP, int MS>
__global__ __launch_bounds__(256) void edge_kernel(
    const float* __restrict__ h,
    const float* __restrict__ efeats,
    const int* __restrict__ src,
    const int* __restrict__ eidS,
    const int* __restrict__ dS,
    const float* __restrict__ W,
    const float* __restrict__ b,
    float* __restrict__ agg)
{
    constexpr int K   = FINP + 64;        // padded input length
    constexpr int F4  = FOUTP / 4;
    constexpr int NH  = (FINP + 15) / 16; // h chunks (last may be short)
    constexpr int NCH = NH + 4;           // + 4 e chunks of 16
    constexpr int ST  = 17;               // stage row stride (dwords, odd)
    static_assert(128 * MS + 64 <= 512 * ST, "msg buf exceeds sbuf");

    __shared__ float4 Wl[K * F4];
    __shared__ float  sbuf[512 * ST];     // union: staged chunks / msg
    __shared__ float  bl[FOUTP];
    __shared__ int    dseg[512];

    const int tid = threadIdx.x;

    // ---- stage W: rows [0,FIN)=h-part, [FIN,FINP)=0, [FINP,FINP+64)=e-part
    for (int idx = tid; idx < K * FOUTP; idx += 256) {
        int k = idx / FOUTP;
        int j = idx - k * FOUTP;
        float v = 0.f;
        if (j < FOUT) {
            if (k < FIN)        v = W[k * FOUT + j];
            else if (k >= FINP) v = W[(FIN + (k - FINP)) * FOUT + j];
        }
        reinterpret_cast<float*>(Wl)[idx] = v;
    }
    if (tid < FOUTP) bl[tid] = (tid < FOUT) ? b[tid] : 0.f;
    {
        const long long pb = (long long)blockIdx.x * 512;
        dseg[tid]       = dS[pb + tid];
        dseg[tid + 256] = dS[pb + 256 + tid];
    }

    const long long p0 = (long long)blockIdx.x * 512 + tid;
    const int eid0 = eidS[p0], eid1 = eidS[p0 + 256];
    const int s0 = src[eid0],  s1 = src[eid1];
    const float* hr0 = h + (long long)s0 * FINP;
    const float* hr1 = h + (long long)s1 * FINP;
    const float* er0 = efeats + (long long)eid0 * 64;
    const float* er1 = efeats + (long long)eid1 * 64;

    __syncthreads();

    float4 acc0[F4], acc1[F4];
    #pragma unroll
    for (int j4 = 0; j4 < F4; j4++) {
        acc0[j4] = reinterpret_cast<float4*>(bl)[j4];
        acc1[j4] = acc0[j4];
    }

    const int t0 = tid * ST;
    const int t1 = (tid + 256) * ST;

    for (int c = 0; c < NCH; ++c) {
        const int off = (c < NH) ? c * 16 : FINP + (c - NH) * 16;
        int lenh = FINP - c * 16; if (lenh > 16) lenh = 16;
        const int len = (c < NH) ? lenh : 16;
        const float* sp0 = (c < NH) ? hr0 + off : er0 + (off - FINP);
        const float* sp1 = (c < NH) ? hr1 + off : er1 + (off - FINP);

        // stage: back-to-back dwordx4 bursts into thread-private LDS slots
        for (int f = 0; f < len / 4; ++f) {
            float4 v0 = *reinterpret_cast<const float4*>(sp0 + 4 * f);
            float4 v1 = *reinterpret_cast<const float4*>(sp1 + 4 * f);
            float* d0 = &sbuf[t0 + 4 * f];
            float* d1 = &sbuf[t1 + 4 * f];
            d0[0] = v0.x; d0[1] = v0.y; d0[2] = v0.z; d0[3] = v0.w;
            d1[0] = v1.x; d1[1] = v1.y; d1[2] = v1.z; d1[3] = v1.w;
        }
        __syncthreads();   // all stage loads complete before any consume

        // consume: runtime trip count + unroll 1 => bounded VGPR pressure
        #pragma unroll 1
        for (int k = 0; k < len; ++k) {
            const float x0 = sbuf[t0 + k];
            const float x1 = sbuf[t1 + k];
            const float4* wrow = &Wl[(off + k) * F4];
            #pragma unroll
            for (int j4 = 0; j4 < F4; j4++) {
                float4 w = wrow[j4];
                fma4(acc0[j4], w, x0);
                fma4(acc1[j4], w, x1);
            }
        }
        // no trailing barrier: each thread re-stages only its OWN slots
    }

    // ---- epilogue: 4 batches of 128 messages, segmented reduce by dst ----
    const int lane = tid & 63;
    const int wv   = tid >> 6;

    #pragma unroll 1
    for (int bb = 0; bb < 4; ++bb) {
        __syncthreads();   // prev batch reads (or consume phase) done
        if ((tid >> 7) == (bb & 1)) {
            const int r = tid & 127;
            float* mrow = &sbuf[r * MS];
            if (bb < 2) {
                #pragma unroll
                for (int j4 = 0; j4 < F4; j4++) {
                    if (4 * j4 + 0 < FOUT) mrow[4 * j4 + 0] = fmaxf(acc0[j4].x, 0.f);
                    if (4 * j4 + 1 < FOUT) mrow[4 * j4 + 1] = fmaxf(acc0[j4].y, 0.f);
                    if (4 * j4 + 2 < FOUT) mrow[4 * j4 + 2] = fmaxf(acc0[j4].z, 0.f);
                    if (4 * j4 + 3 < FOUT) mrow[4 * j4 + 3] = fmaxf(acc0[j4].w, 0.f);
                }
            } else {
                #pragma unroll
                for (int j4 = 0; j4 < F4; j4++) {
                    if (4 * j4 + 0 < FOUT) mrow[4 * j4 + 0] = fmaxf(acc1[j4].x, 0.f);
                    if (4 * j4 + 1 < FOUT) mrow[4 * j4 + 1] = fmaxf(acc1[j4].y, 0.f);
                    if (4 * j4 + 2 < FOUT) mrow[4 * j4 + 2] = fmaxf(acc1[j4].z, 0.f);
                    if (4 * j4 + 3 < FOUT) mrow[4 * j4 + 3] = fmaxf(acc1[j4].w, 0.f);
                }
            }
        }
        __syncthreads();

        const int rbase = bb * 128;
        for (int r0 = wv * 32; r0 < wv * 32 + 32; ++r0) {
            int dr = dseg[rbase + r0];
            if (r0 > 0 && dseg[rbase + r0 - 1] == dr) continue; // not seg start
            float s = 0.f;
            int rr = r0;
            while (true) {
                s += sbuf[rr * MS + lane];
                ++rr;
                if (rr >= 128 || dseg[rbase + rr] != dr) break;
            }
            if (lane < FOUT) atomicAdd(agg + (long long)dr * FOUT + lane, s);
        }
    }
}

// ===========================================================================
// Node kernel: out = relu(cat(h, agg) @ W + b), one thread per node.
// ===========================================================================
template<int FH, int FHP, int FAGG, int FOUT, int FOUTP>
__global__ __launch_bounds__(256) void node_kernel(
    const float* __restrict__ h,
    const float* __restrict__ agg,
    const float* __restrict__ W,
    const float* __restrict__ b,
    float* __restrict__ out,
    int nNodes)
{
    constexpr int K  = FH + FAGG;
    constexpr int F4 = FOUTP / 4;

    __shared__ float4 Wl[K * F4];
    __shared__ float4 bl[F4];

    const int tid = threadIdx.x;
    for (int idx = tid; idx < K * FOUTP; idx += 256) {
        int k = idx / FOUTP;
        int j = idx - k * FOUTP;
        reinterpret_cast<float*>(Wl)[idx] = (j < FOUT) ? W[k * FOUT + j] : 0.f;
    }
    for (int idx = tid; idx < FOUTP; idx += 256)
        reinterpret_cast<float*>(bl)[idx] = (idx < FOUT) ? b[idx] : 0.f;
    __syncthreads();

    const int n = blockIdx.x * 256 + tid;
    if (n >= nNodes) return;

    float4 acc[F4];
    #pragma unroll
    for (int j4 = 0; j4 < F4; j4++) acc[j4] = bl[j4];

    const float* hrow = h + (long long)n * FHP;
    #pragma unroll 1
    for (int k = 0; k < FH; k++) {
        float xk = hrow[k];
        const float4* wrow = &Wl[k * F4];
        #pragma unroll
        for (int j4 = 0; j4 < F4; j4++) fma4(acc[j4], wrow[j4], xk);
    }
    const float* arow = agg + (long long)n * FAGG;
    #pragma unroll 1
    for (int k = 0; k < FAGG; k++) {
        float xk = arow[k];
        const float4* wrow = &Wl[(FH + k) * F4];
        #pragma unroll
        for (int j4 = 0; j4 < F4; j4++) fma4(acc[j4], wrow[j4], xk);
    }

    float4* orow = reinterpret_cast<float4*>(out + (long long)n * FOUTP);
    #pragma unroll
    for (int j4 = 0; j4 < F4; j4++) {
        float4 a = acc[j4];
        a.x = fmaxf(a.x, 0.f); a.y = fmaxf(a.y, 0.f);
        a.z = fmaxf(a.z, 0.f); a.w = fmaxf(a.w, 0.f);
        orow[j4] = a;
    }
}

extern "C" void kernel_launch(void* const* d_in, const int* in_sizes, int n_in,
                              void* d_out, int out_size, void* d_ws, size_t ws_size,
                              hipStream_t stream)
{
    const float* nfeats = (const float*)d_in[0];
    const float* efeats = (const float*)d_in[1];
    const int*   src    = (const int*)d_in[2];
    const int*   dst    = (const int*)d_in[3];
    const float* Wm1 = (const float*)d_in[4],  *bm1 = (const float*)d_in[5];
    const float* Wa1 = (const float*)d_in[6],  *ba1 = (const float*)d_in[7];
    const float* Wm2 = (const float*)d_in[8],  *bm2 = (const float*)d_in[9];
    const float* Wa2 = (const float*)d_in[10], *ba2 = (const float*)d_in[11];
    const float* Wm3 = (const float*)d_in[12], *bm3 = (const float*)d_in[13];
    const float* Wa3 = (const float*)d_in[14], *ba3 = (const float*)d_in[15];
    float* out = (float*)d_out;

    constexpr int N = 100000;
    constexpr int E = 3200000;                      // divisible by 512
    constexpr int SCAN_BLOCKS = (N + 1023) / 1024;  // 98

    float* ws   = (float*)d_ws;
    float* h1   = ws;                            // N x 52
    float* h2   = h1 + (size_t)N * 52;           // N x 28
    float* agg  = h2 + (size_t)N * 28;           // N x 52
    int* counts = (int*)(agg + (size_t)N * 52);  // N
    int* cursor = counts + N;                    // N
    int* bsums  = cursor + N;                    // 128
    int* eidS   = bsums + 128;                   // E
    int* dS     = eidS + E;                      // E

    // ---- CSR build (counting sort by dst) ----
    hipMemsetAsync(counts, 0, (size_t)N * sizeof(int), stream);
    hist_kernel<<<2048, 256, 0, stream>>>(dst, counts, E);
    scan_block<<<SCAN_BLOCKS, 1024, 0, stream>>>(counts, cursor, bsums, N);
    scan_small<<<1, 64, 0, stream>>>(bsums, SCAN_BLOCKS);
    add_offsets<<<SCAN_BLOCKS, 1024, 0, stream>>>(cursor, bsums, N);
    scatter_kernel<<<2048, 256, 0, stream>>>(dst, cursor, eidS, dS, E);

    const int EB = E / 512;          // 512 edges per block
    const int NB = (N + 255) / 256;

    // ---- layer 1 ----  edge: 64(+64) -> 50 (MS=51); node: 64+50 -> 50
    hipMemsetAsync(agg, 0, (size_t)N * 52 * sizeof(float), stream);
    edge_kernel<64, 64, 50, 52, 51><<<EB, 256, 0, stream>>>(nfeats, efeats, src, eidS, dS, Wm1, bm1, agg);
    node_kernel<64, 64, 50, 50, 52><<<NB, 256, 0, stream>>>(nfeats, agg, Wa1, ba1, h1, N);

    // ---- layer 2 ----  edge: 50(+64) -> 25 (MS=25); node: 50+25 -> 25
    hipMemsetAsync(agg, 0, (size_t)N * 52 * sizeof(float), stream);
    edge_kernel<50, 52, 25, 28, 25><<<EB, 256, 0, stream>>>(h1, efeats, src, eidS, dS, Wm2, bm2, agg);
    node_kernel<50, 52, 25, 25, 28><<<NB, 256, 0, stream>>>(h1, agg, Wa2, ba2, h2, N);

    // ---- layer 3 ----  edge: 25(+64) -> 32 (MS=33); node: 25+32 -> 32
    hipMemsetAsync(agg, 0, (size_t)N * 52 * sizeof(float), stream);
    edge_kernel<25, 28, 32, 32, 33><<<EB, 256, 0, stream>>>(h2, efeats, src, eidS, dS, Wm3, bm3, agg);
    node_kernel<25, 28, 32, 32, 32><<<NB, 256, 0, stream>>>(h2, agg, Wa3, ba3, out, N);
}

// Round 7
// 2577.517 us; speedup vs baseline: 11.1656x; 1.1300x over previous
//
#include <hip/hip_runtime.h>

#define DEVINL __device__ __forceinline__

DEVINL void fma4(float4& a, const float4 w, const float x) {
    a.x += w.x * x; a.y += w.y * x; a.z += w.z * x; a.w += w.w * x;
}

// ===========================================================================
// CSR build: counting sort of edges by dst.
// ===========================================================================
__global__ __launch_bounds__(256) void hist_kernel(const int* __restrict__ d,
                                                   int* __restrict__ counts, int n) {
    for (int i = blockIdx.x * 256 + threadIdx.x; i < n; i += gridDim.x * 256)
        atomicAdd(&counts[d[i]], 1);
}

__global__ __launch_bounds__(1024) void scan_block(const int* __restrict__ in,
                                                   int* __restrict__ out,
                                                   int* __restrict__ bsums, int n) {
    __shared__ int buf[2][1024];
    const int t = threadIdx.x;
    const int i = blockIdx.x * 1024 + t;
    const int v = (i < n) ? in[i] : 0;
    int cur = 0;
    buf[0][t] = v;
    __syncthreads();
    #pragma unroll
    for (int s = 1; s < 1024; s <<= 1) {
        int x = buf[cur][t];
        if (t >= s) x += buf[cur][t - s];
        buf[cur ^ 1][t] = x;
        cur ^= 1;
        __syncthreads();
    }
    if (i < n) out[i] = buf[cur][t] - v;            // exclusive
    if (t == 1023) bsums[blockIdx.x] = buf[cur][t]; // block total
}

__global__ void scan_small(int* __restrict__ bs, int nb) {
    if (blockIdx.x == 0 && threadIdx.x == 0) {
        int acc = 0;
        for (int i = 0; i < nb; i++) { int v = bs[i]; bs[i] = acc; acc += v; }
    }
}

__global__ __launch_bounds__(1024) void add_offsets(int* __restrict__ out,
                                                    const int* __restrict__ bs, int n) {
    int i = blockIdx.x * 1024 + threadIdx.x;
    if (i < n) out[i] += bs[blockIdx.x];
}

__global__ __launch_bounds__(256) void scatter_kernel(const int* __restrict__ d,
                                                      int* __restrict__ cursor,
                                                      int* __restrict__ eidS,
                                                      int* __restrict__ dS, int n) {
    for (int i = blockIdx.x * 256 + threadIdx.x; i < n; i += gridDim.x * 256) {
        int dd = d[i];
        int pos = atomicAdd(&cursor[dd], 1);
        eidS[pos] = i;
        dS[pos] = dd;
    }
}

// ===========================================================================
// Pack W into a zero-padded [KP][FOUTP] fp32 table (16B-aligned rows):
// rows [0,FIN) = h-part, [FIN,FINP) = 0, [FINP,FINP+64) = e-part; cols >=
// FOUT are 0. Enables uniform (scalar-pipe) float4 loads in the edge kernel.
// ===========================================================================
template<int FIN, int FINP, int FOUT, int FOUTP, int KP>
__global__ __launch_bounds__(256) void pack_w(const float* __restrict__ W,
                                              float* __restrict__ Wp) {
    int idx = blockIdx.x * 256 + threadIdx.x;
    if (idx >= KP * FOUTP) return;
    int k = idx / FOUTP, j = idx - k * FOUTP;
    float v = 0.f;
    if (j < FOUT) {
        if (k < FIN)        v = W[k * FOUT + j];
        else if (k >= FINP) v = W[(FIN + (k - FINP)) * FOUT + j];
    }
    Wp[idx] = v;
}

// ===========================================================================
// Edge kernel (dst-sorted, chunk-staged, 2 edges/thread, W via uniform
// global loads):
//   256 threads / 512 edges per block. Gathered input rows are staged into
//   thread-private LDS slots in 16-dword chunks (burst dwordx4, post-stage
//   barrier => each cache line fetched once). W rows are read directly from
//   the packed global table with wave-uniform addresses -> scalar-pipe
//   (s_load) candidates; LDS pipe carries only the 2 x-reads per k. No W
//   tile in LDS => ~37 KB LDS => 4 blocks/CU.
//   Epilogue: 4 batches of 128 messages -> LDS -> segmented reduce by sorted
//   dst -> ~1 atomic per (segment, feature).
// Grid sized exactly: nEdges % 512 == 0.
// ===========================================================================
template<int FIN, int FINP, int FOUT, int FOUTP, int MS>
__global__ __launch_bounds__(256) void edge_kernel(
    const float* __restrict__ h,
    const float* __restrict__ efeats,
    const int* __restrict__ src,
    const int* __restrict__ eidS,
    const int* __restrict__ dS,
    const float* __restrict__ Wp,   // packed [FINP+64][FOUTP]
    const float* __restrict__ b,
    float* __restrict__ agg)
{
    constexpr int F4  = FOUTP / 4;
    constexpr int NH  = (FINP + 15) / 16; // h chunks (last may be short)
    constexpr int NCH = NH + 4;           // + 4 e chunks of 16
    constexpr int ST  = 17;               // stage row stride (dwords, odd)
    static_assert(128 * MS + 64 <= 512 * ST, "msg buf exceeds sbuf");

    __shared__ float  sbuf[512 * ST];     // union: staged chunks / msg
    __shared__ float  bl[FOUTP];
    __shared__ int    dseg[512];

    const int tid = threadIdx.x;

    if (tid < FOUTP) bl[tid] = (tid < FOUT) ? b[tid] : 0.f;
    {
        const long long pb = (long long)blockIdx.x * 512;
        dseg[tid]       = dS[pb + tid];
        dseg[tid + 256] = dS[pb + 256 + tid];
    }

    const long long p0 = (long long)blockIdx.x * 512 + tid;
    const int eid0 = eidS[p0], eid1 = eidS[p0 + 256];
    const int s0 = src[eid0],  s1 = src[eid1];
    const float* hr0 = h + (long long)s0 * FINP;
    const float* hr1 = h + (long long)s1 * FINP;
    const float* er0 = efeats + (long long)eid0 * 64;
    const float* er1 = efeats + (long long)eid1 * 64;
    const float4* Wp4 = reinterpret_cast<const float4*>(Wp);

    __syncthreads();

    float4 acc0[F4], acc1[F4];
    #pragma unroll
    for (int j4 = 0; j4 < F4; j4++) {
        acc0[j4] = reinterpret_cast<float4*>(bl)[j4];
        acc1[j4] = acc0[j4];
    }

    const int t0 = tid * ST;
    const int t1 = (tid + 256) * ST;

    for (int c = 0; c < NCH; ++c) {
        const int off = (c < NH) ? c * 16 : FINP + (c - NH) * 16;
        int lenh = FINP - c * 16; if (lenh > 16) lenh = 16;
        const int len = (c < NH) ? lenh : 16;
        const float* sp0 = (c < NH) ? hr0 + off : er0 + (off - FINP);
        const float* sp1 = (c < NH) ? hr1 + off : er1 + (off - FINP);

        // stage: back-to-back dwordx4 bursts into thread-private LDS slots
        for (int f = 0; f < len / 4; ++f) {
            float4 v0 = *reinterpret_cast<const float4*>(sp0 + 4 * f);
            float4 v1 = *reinterpret_cast<const float4*>(sp1 + 4 * f);
            float* d0 = &sbuf[t0 + 4 * f];
            float* d1 = &sbuf[t1 + 4 * f];
            d0[0] = v0.x; d0[1] = v0.y; d0[2] = v0.z; d0[3] = v0.w;
            d1[0] = v1.x; d1[1] = v1.y; d1[2] = v1.z; d1[3] = v1.w;
        }
        __syncthreads();   // all stage loads complete before any consume

        // consume: x from LDS (2 b32/k); W rows from global with wave-uniform
        // addresses (scalar-pipe candidates). unroll 1 => bounded VGPRs.
        #pragma unroll 1
        for (int k = 0; k < len; ++k) {
            const float x0 = sbuf[t0 + k];
            const float x1 = sbuf[t1 + k];
            const float4* wrow = &Wp4[(off + k) * F4];
            #pragma unroll
            for (int j4 = 0; j4 < F4; j4++) {
                float4 w = wrow[j4];
                fma4(acc0[j4], w, x0);
                fma4(acc1[j4], w, x1);
            }
        }
        // no trailing barrier: each thread re-stages only its OWN slots
    }

    // ---- epilogue: 4 batches of 128 messages, segmented reduce by dst ----
    const int lane = tid & 63;
    const int wv   = tid >> 6;

    #pragma unroll 1
    for (int bb = 0; bb < 4; ++bb) {
        __syncthreads();   // prev batch reads (or consume phase) done
        if ((tid >> 7) == (bb & 1)) {
            const int r = tid & 127;
            float* mrow = &sbuf[r * MS];
            if (bb < 2) {
                #pragma unroll
                for (int j4 = 0; j4 < F4; j4++) {
                    if (4 * j4 + 0 < FOUT) mrow[4 * j4 + 0] = fmaxf(acc0[j4].x, 0.f);
                    if (4 * j4 + 1 < FOUT) mrow[4 * j4 + 1] = fmaxf(acc0[j4].y, 0.f);
                    if (4 * j4 + 2 < FOUT) mrow[4 * j4 + 2] = fmaxf(acc0[j4].z, 0.f);
                    if (4 * j4 + 3 < FOUT) mrow[4 * j4 + 3] = fmaxf(acc0[j4].w, 0.f);
                }
            } else {
                #pragma unroll
                for (int j4 = 0; j4 < F4; j4++) {
                    if (4 * j4 + 0 < FOUT) mrow[4 * j4 + 0] = fmaxf(acc1[j4].x, 0.f);
                    if (4 * j4 + 1 < FOUT) mrow[4 * j4 + 1] = fmaxf(acc1[j4].y, 0.f);
                    if (4 * j4 + 2 < FOUT) mrow[4 * j4 + 2] = fmaxf(acc1[j4].z, 0.f);
                    if (4 * j4 + 3 < FOUT) mrow[4 * j4 + 3] = fmaxf(acc1[j4].w, 0.f);
                }
            }
        }
        __syncthreads();

        const int rbase = bb * 128;
        for (int r0 = wv * 32; r0 < wv * 32 + 32; ++r0) {
            int dr = dseg[rbase + r0];
            if (r0 > 0 && dseg[rbase + r0 - 1] == dr) continue; // not seg start
            float s = 0.f;
            int rr = r0;
            while (true) {
                s += sbuf[rr * MS + lane];
                ++rr;
                if (rr >= 128 || dseg[rbase + rr] != dr) break;
            }
            if (lane < FOUT) atomicAdd(agg + (long long)dr * FOUT + lane, s);
        }
    }
}

// ===========================================================================
// Node kernel: out = relu(cat(h, agg) @ W + b), one thread per node.
// ===========================================================================
template<int FH, int FHP, int FAGG, int FOUT, int FOUTP>
__global__ __launch_bounds__(256) void node_kernel(
    const float* __restrict__ h,
    const float* __restrict__ agg,
    const float* __restrict__ W,
    const float* __restrict__ b,
    float* __restrict__ out,
    int nNodes)
{
    constexpr int K  = FH + FAGG;
    constexpr int F4 = FOUTP / 4;

    __shared__ float4 Wl[K * F4];
    __shared__ float4 bl[F4];

    const int tid = threadIdx.x;
    for (int idx = tid; idx < K * FOUTP; idx += 256) {
        int k = idx / FOUTP;
        int j = idx - k * FOUTP;
        reinterpret_cast<float*>(Wl)[idx] = (j < FOUT) ? W[k * FOUT + j] : 0.f;
    }
    for (int idx = tid; idx < FOUTP; idx += 256)
        reinterpret_cast<float*>(bl)[idx] = (idx < FOUT) ? b[idx] : 0.f;
    __syncthreads();

    const int n = blockIdx.x * 256 + tid;
    if (n >= nNodes) return;

    float4 acc[F4];
    #pragma unroll
    for (int j4 = 0; j4 < F4; j4++) acc[j4] = bl[j4];

    const float* hrow = h + (long long)n * FHP;
    #pragma unroll 1
    for (int k = 0; k < FH; k++) {
        float xk = hrow[k];
        const float4* wrow = &Wl[k * F4];
        #pragma unroll
        for (int j4 = 0; j4 < F4; j4++) fma4(acc[j4], wrow[j4], xk);
    }
    const float* arow = agg + (long long)n * FAGG;
    #pragma unroll 1
    for (int k = 0; k < FAGG; k++) {
        float xk = arow[k];
        const float4* wrow = &Wl[(FH + k) * F4];
        #pragma unroll
        for (int j4 = 0; j4 < F4; j4++) fma4(acc[j4], wrow[j4], xk);
    }

    float4* orow = reinterpret_cast<float4*>(out + (long long)n * FOUTP);
    #pragma unroll
    for (int j4 = 0; j4 < F4; j4++) {
        float4 a = acc[j4];
        a.x = fmaxf(a.x, 0.f); a.y = fmaxf(a.y, 0.f);
        a.z = fmaxf(a.z, 0.f); a.w = fmaxf(a.w, 0.f);
        orow[j4] = a;
    }
}

extern "C" void kernel_launch(void* const* d_in, const int* in_sizes, int n_in,
                              void* d_out, int out_size, void* d_ws, size_t ws_size,
                              hipStream_t stream)
{
    const float* nfeats = (const float*)d_in[0];
    const float* efeats = (const float*)d_in[1];
    const int*   src    = (const int*)d_in[2];
    const int*   dst    = (const int*)d_in[3];
    const float* Wm1 = (const float*)d_in[4],  *bm1 = (const float*)d_in[5];
    const float* Wa1 = (const float*)d_in[6],  *ba1 = (const float*)d_in[7];
    const float* Wm2 = (const float*)d_in[8],  *bm2 = (const float*)d_in[9];
    const float* Wa2 = (const float*)d_in[10], *ba2 = (const float*)d_in[11];
    const float* Wm3 = (const float*)d_in[12], *bm3 = (const float*)d_in[13];
    const float* Wa3 = (const float*)d_in[14], *ba3 = (const float*)d_in[15];
    float* out = (float*)d_out;

    constexpr int N = 100000;
    constexpr int E = 3200000;                      // divisible by 512
    constexpr int SCAN_BLOCKS = (N + 1023) / 1024;  // 98

    float* ws   = (float*)d_ws;
    float* h1   = ws;                            // N x 52
    float* h2   = h1 + (size_t)N * 52;           // N x 28
    float* agg  = h2 + (size_t)N * 28;           // N x 52
    int* counts = (int*)(agg + (size_t)N * 52);  // N
    int* cursor = counts + N;                    // N
    int* bsums  = cursor + N;                    // 128
    int* eidS   = bsums + 128;                   // E
    int* dS     = eidS + E;                      // E
    float* Wp1  = (float*)(dS + E);              // 128 x 52
    float* Wp2  = Wp1 + 128 * 52;                // 116 x 28
    float* Wp3  = Wp2 + 116 * 28;                // 92 x 32

    // ---- pack W tables (padded, 16B-aligned rows) ----
    pack_w<64, 64, 50, 52, 128><<<(128 * 52 + 255) / 256, 256, 0, stream>>>(Wm1, Wp1);
    pack_w<50, 52, 25, 28, 116><<<(116 * 28 + 255) / 256, 256, 0, stream>>>(Wm2, Wp2);
    pack_w<25, 28, 32, 32,  92><<<( 92 * 32 + 255) / 256, 256, 0, stream>>>(Wm3, Wp3);

    // ---- CSR build (counting sort by dst) ----
    hipMemsetAsync(counts, 0, (size_t)N * sizeof(int), stream);
    hist_kernel<<<2048, 256, 0, stream>>>(dst, counts, E);
    scan_block<<<SCAN_BLOCKS, 1024, 0, stream>>>(counts, cursor, bsums, N);
    scan_small<<<1, 64, 0, stream>>>(bsums, SCAN_BLOCKS);
    add_offsets<<<SCAN_BLOCKS, 1024, 0, stream>>>(cursor, bsums, N);
    scatter_kernel<<<2048, 256, 0, stream>>>(dst, cursor, eidS, dS, E);

    const int EB = E / 512;          // 512 edges per block
    const int NB = (N + 255) / 256;

    // ---- layer 1 ----  edge: 64(+64) -> 50 (MS=51); node: 64+50 -> 50
    hipMemsetAsync(agg, 0, (size_t)N * 52 * sizeof(float), stream);
    edge_kernel<64, 64, 50, 52, 51><<<EB, 256, 0, stream>>>(nfeats, efeats, src, eidS, dS, Wp1, bm1, agg);
    node_kernel<64, 64, 50, 50, 52><<<NB, 256, 0, stream>>>(nfeats, agg, Wa1, ba1, h1, N);

    // ---- layer 2 ----  edge: 50(+64) -> 25 (MS=25); node: 50+25 -> 25
    hipMemsetAsync(agg, 0, (size_t)N * 52 * sizeof(float), stream);
    edge_kernel<50, 52, 25, 28, 25><<<EB, 256, 0, stream>>>(h1, efeats, src, eidS, dS, Wp2, bm2, agg);
    node_kernel<50, 52, 25, 25, 28><<<NB, 256, 0, stream>>>(h1, agg, Wa2, ba2, h2, N);

    // ---- layer 3 ----  edge: 25(+64) -> 32 (MS=33); node: 25+32 -> 32
    hipMemsetAsync(agg, 0, (size_t)N * 52 * sizeof(float), stream);
    edge_kernel<25, 28, 32, 32, 33><<<EB, 256, 0, stream>>>(h2, efeats, src, eidS, dS, Wp3, bm3, agg);
    node_kernel<25, 28, 32, 32, 32><<<NB, 256, 0, stream>>>(h2, agg, Wa3, ba3, out, N);
}

// Round 8
// 2170.026 us; speedup vs baseline: 13.2623x; 1.1878x over previous
//
#include <hip/hip_runtime.h>

#define DEVINL __device__ __forceinline__

DEVINL void fma4(float4& a, const float4 w, const float x) {
    a.x += w.x * x; a.y += w.y * x; a.z += w.z * x; a.w += w.w * x;
}

// ===========================================================================
// CSR build: counting sort of edges by dst.
// ===========================================================================
__global__ __launch_bounds__(256) void hist_kernel(const int* __restrict__ d,
                                                   int* __restrict__ counts, int n) {
    for (int i = blockIdx.x * 256 + threadIdx.x; i < n; i += gridDim.x * 256)
        atomicAdd(&counts[d[i]], 1);
}

__global__ __launch_bounds__(1024) void scan_block(const int* __restrict__ in,
                                                   int* __restrict__ out,
                                                   int* __restrict__ bsums, int n) {
    __shared__ int buf[2][1024];
    const int t = threadIdx.x;
    const int i = blockIdx.x * 1024 + t;
    const int v = (i < n) ? in[i] : 0;
    int cur = 0;
    buf[0][t] = v;
    __syncthreads();
    #pragma unroll
    for (int s = 1; s < 1024; s <<= 1) {
        int x = buf[cur][t];
        if (t >= s) x += buf[cur][t - s];
        buf[cur ^ 1][t] = x;
        cur ^= 1;
        __syncthreads();
    }
    if (i < n) out[i] = buf[cur][t] - v;            // exclusive
    if (t == 1023) bsums[blockIdx.x] = buf[cur][t]; // block total
}

__global__ void scan_small(int* __restrict__ bs, int nb) {
    if (blockIdx.x == 0 && threadIdx.x == 0) {
        int acc = 0;
        for (int i = 0; i < nb; i++) { int v = bs[i]; bs[i] = acc; acc += v; }
    }
}

__global__ __launch_bounds__(1024) void add_offsets(int* __restrict__ out,
                                                    const int* __restrict__ bs, int n) {
    int i = blockIdx.x * 1024 + threadIdx.x;
    if (i < n) out[i] += bs[blockIdx.x];
}

__global__ __launch_bounds__(256) void scatter_kernel(const int* __restrict__ d,
                                                      int* __restrict__ cursor,
                                                      int* __restrict__ eidS,
                                                      int* __restrict__ dS, int n) {
    for (int i = blockIdx.x * 256 + threadIdx.x; i < n; i += gridDim.x * 256) {
        int dd = d[i];
        int pos = atomicAdd(&cursor[dd], 1);
        eidS[pos] = i;
        dS[pos] = dd;
    }
}

// ===========================================================================
// pack_we: e-part of Wm (rows [FIN, FIN+64)) -> padded [64][FOUTP] table.
// ===========================================================================
template<int FIN, int FOUT, int FOUTP>
__global__ __launch_bounds__(256) void pack_we(const float* __restrict__ W,
                                               float* __restrict__ Wp) {
    int idx = blockIdx.x * 256 + threadIdx.x;
    if (idx >= 64 * FOUTP) return;
    int k = idx / FOUTP, j = idx - k * FOUTP;
    Wp[idx] = (j < FOUT) ? W[(FIN + k) * FOUT + j] : 0.f;
}

// ===========================================================================
// gemv_g: g = x @ W(h-part rows [0,FIN)) + b, padded to FOUTP. One thread
// per node. Used once for layer 1 (layers 2/3 fuse this into node_kernel).
// ===========================================================================
template<int FIN, int FOUT, int FOUTP>
__global__ __launch_bounds__(256) void gemv_g(
    const float* __restrict__ x,   // [N][FIN]
    const float* __restrict__ W,   // rows [0,FIN) of [.. ][FOUT]
    const float* __restrict__ b,
    float* __restrict__ g, int nNodes)
{
    constexpr int F4 = FOUTP / 4;
    __shared__ float4 Wl[FIN * F4];
    __shared__ float  bl[FOUTP];
    const int tid = threadIdx.x;
    for (int idx = tid; idx < FIN * FOUTP; idx += 256) {
        int k = idx / FOUTP, j = idx - k * FOUTP;
        reinterpret_cast<float*>(Wl)[idx] = (j < FOUT) ? W[k * FOUT + j] : 0.f;
    }
    for (int idx = tid; idx < FOUTP; idx += 256)
        bl[idx] = (idx < FOUT) ? b[idx] : 0.f;
    __syncthreads();
    const int n = blockIdx.x * 256 + tid;
    if (n >= nNodes) return;
    float4 acc[F4];
    #pragma unroll
    for (int j4 = 0; j4 < F4; j4++) acc[j4] = reinterpret_cast<float4*>(bl)[j4];
    const float* xr = x + (long long)n * FIN;
    #pragma unroll 1
    for (int k = 0; k < FIN; ++k) {
        float xk = xr[k];
        const float4* wrow = &Wl[k * F4];
        #pragma unroll
        for (int j4 = 0; j4 < F4; j4++) fma4(acc[j4], wrow[j4], xk);
    }
    float4* gr = reinterpret_cast<float4*>(g + (long long)n * FOUTP);
    #pragma unroll
    for (int j4 = 0; j4 < F4; j4++) gr[j4] = acc[j4];
}

// ===========================================================================
// Edge kernel (decomposed): m = relu(g[src] + e @ We). K=64 for all layers.
//   256 threads / 512 edges per block, 2 edges/thread. g[src] rows are
//   burst-loaded directly INTO the accumulator registers (13/7/8 dwordx4,
//   line-once). e rows staged into thread-private LDS slots in 4 chunks of
//   16 dwords (burst + barrier => line-once). We read from packed global
//   table with wave-uniform addresses (scalar-pipe candidates).
//   Epilogue: 4 batches of 128 messages -> LDS -> segmented reduce by
//   sorted dst -> ~1 atomic per (segment, feature).
// Grid sized exactly: nEdges % 512 == 0.
// ===========================================================================
template<int FOUT, int FOUTP, int MS>
__global__ __launch_bounds__(256) void edge_kernel(
    const float* __restrict__ g,      // [N][FOUTP] = h@Wh + b (padded)
    const float* __restrict__ efeats,
    const int* __restrict__ src,
    const int* __restrict__ eidS,
    const int* __restrict__ dS,
    const float* __restrict__ Wp,     // packed [64][FOUTP] e-part
    float* __restrict__ agg)
{
    constexpr int F4 = FOUTP / 4;
    constexpr int ST = 17;            // stage row stride (dwords, odd)
    static_assert(128 * MS + 64 <= 512 * ST, "msg buf exceeds sbuf");

    __shared__ float sbuf[512 * ST];  // union: staged e chunks / msg
    __shared__ int   dseg[512];

    const int tid = threadIdx.x;
    {
        const long long pb = (long long)blockIdx.x * 512;
        dseg[tid]       = dS[pb + tid];
        dseg[tid + 256] = dS[pb + 256 + tid];
    }

    const long long p0 = (long long)blockIdx.x * 512 + tid;
    const int eid0 = eidS[p0], eid1 = eidS[p0 + 256];
    const int s0 = src[eid0],  s1 = src[eid1];
    const float4* gr0 = reinterpret_cast<const float4*>(g + (long long)s0 * FOUTP);
    const float4* gr1 = reinterpret_cast<const float4*>(g + (long long)s1 * FOUTP);
    const float*  er0 = efeats + (long long)eid0 * 64;
    const float*  er1 = efeats + (long long)eid1 * 64;
    const float4* Wp4 = reinterpret_cast<const float4*>(Wp);

    // acc init = g[src] (burst loads straight into the accumulators)
    float4 acc0[F4], acc1[F4];
    #pragma unroll
    for (int j4 = 0; j4 < F4; j4++) acc0[j4] = gr0[j4];
    #pragma unroll
    for (int j4 = 0; j4 < F4; j4++) acc1[j4] = gr1[j4];

    const int t0 = tid * ST;
    const int t1 = (tid + 256) * ST;

    for (int c = 0; c < 4; ++c) {
        const int off = c * 16;
        // stage: back-to-back dwordx4 bursts into thread-private LDS slots
        #pragma unroll
        for (int f = 0; f < 4; ++f) {
            float4 v0 = *reinterpret_cast<const float4*>(er0 + off + 4 * f);
            float4 v1 = *reinterpret_cast<const float4*>(er1 + off + 4 * f);
            float* d0 = &sbuf[t0 + 4 * f];
            float* d1 = &sbuf[t1 + 4 * f];
            d0[0] = v0.x; d0[1] = v0.y; d0[2] = v0.z; d0[3] = v0.w;
            d1[0] = v1.x; d1[1] = v1.y; d1[2] = v1.z; d1[3] = v1.w;
        }
        __syncthreads();   // all stage loads complete before any consume

        // consume: x from LDS; W rows wave-uniform from global
        #pragma unroll 1
        for (int k = 0; k < 16; ++k) {
            const float x0 = sbuf[t0 + k];
            const float x1 = sbuf[t1 + k];
            const float4* wrow = &Wp4[(off + k) * F4];
            #pragma unroll
            for (int j4 = 0; j4 < F4; j4++) {
                float4 w = wrow[j4];
                fma4(acc0[j4], w, x0);
                fma4(acc1[j4], w, x1);
            }
        }
        // no trailing barrier: each thread re-stages only its OWN slots
    }

    // ---- epilogue: 4 batches of 128 messages, segmented reduce by dst ----
    const int lane = tid & 63;
    const int wv   = tid >> 6;

    #pragma unroll 1
    for (int bb = 0; bb < 4; ++bb) {
        __syncthreads();   // prev batch reads (or consume phase) done
        if ((tid >> 7) == (bb & 1)) {
            const int r = tid & 127;
            float* mrow = &sbuf[r * MS];
            if (bb < 2) {
                #pragma unroll
                for (int j4 = 0; j4 < F4; j4++) {
                    if (4 * j4 + 0 < FOUT) mrow[4 * j4 + 0] = fmaxf(acc0[j4].x, 0.f);
                    if (4 * j4 + 1 < FOUT) mrow[4 * j4 + 1] = fmaxf(acc0[j4].y, 0.f);
                    if (4 * j4 + 2 < FOUT) mrow[4 * j4 + 2] = fmaxf(acc0[j4].z, 0.f);
                    if (4 * j4 + 3 < FOUT) mrow[4 * j4 + 3] = fmaxf(acc0[j4].w, 0.f);
                }
            } else {
                #pragma unroll
                for (int j4 = 0; j4 < F4; j4++) {
                    if (4 * j4 + 0 < FOUT) mrow[4 * j4 + 0] = fmaxf(acc1[j4].x, 0.f);
                    if (4 * j4 + 1 < FOUT) mrow[4 * j4 + 1] = fmaxf(acc1[j4].y, 0.f);
                    if (4 * j4 + 2 < FOUT) mrow[4 * j4 + 2] = fmaxf(acc1[j4].z, 0.f);
                    if (4 * j4 + 3 < FOUT) mrow[4 * j4 + 3] = fmaxf(acc1[j4].w, 0.f);
                }
            }
        }
        __syncthreads();

        const int rbase = bb * 128;
        for (int r0 = wv * 32; r0 < wv * 32 + 32; ++r0) {
            int dr = dseg[rbase + r0];
            if (r0 > 0 && dseg[rbase + r0 - 1] == dr) continue; // not seg start
            float s = 0.f;
            int rr = r0;
            while (true) {
                s += sbuf[rr * MS + lane];
                ++rr;
                if (rr >= 128 || dseg[rbase + rr] != dr) break;
            }
            if (lane < FOUT) atomicAdd(agg + (long long)dr * FOUT + lane, s);
        }
    }
}

// ===========================================================================
// Node kernel (fused): h_next = relu(cat(h, agg) @ Wa + ba), and (if GOUT>0)
// g_next = h_next @ Wm_next(h-part) + bm_next for the NEXT layer's edges.
// One thread per node; h_next is in registers so the g-GEMV is nearly free.
// ===========================================================================
template<int FH, int FHP, int FAGG, int FOUT, int FOUTP, int GOUT, int GOUTP>
__global__ __launch_bounds__(256) void node_kernel(
    const float* __restrict__ h,
    const float* __restrict__ agg,
    const float* __restrict__ Wa,
    const float* __restrict__ ba,
    const float* __restrict__ Wmn,   // next Wm, h-part rows [0,FOUT)
    const float* __restrict__ bmn,
    float* __restrict__ out,         // [N][FOUTP]
    float* __restrict__ gout,        // [N][GOUTP]
    int nNodes)
{
    constexpr int K  = FH + FAGG;
    constexpr int F4 = FOUTP / 4;
    constexpr int G4 = (GOUT > 0) ? GOUTP / 4 : 1;

    __shared__ float4 Wl[K * F4];
    __shared__ float4 Wg[(GOUT > 0) ? FOUTP * G4 : 1];
    __shared__ float  bl[FOUTP];
    __shared__ float  bg[(GOUT > 0) ? GOUTP : 4];

    const int tid = threadIdx.x;
    for (int idx = tid; idx < K * FOUTP; idx += 256) {
        int k = idx / FOUTP, j = idx - k * FOUTP;
        reinterpret_cast<float*>(Wl)[idx] = (j < FOUT) ? Wa[k * FOUT + j] : 0.f;
    }
    for (int idx = tid; idx < FOUTP; idx += 256)
        bl[idx] = (idx < FOUT) ? ba[idx] : 0.f;
    if constexpr (GOUT > 0) {
        for (int idx = tid; idx < FOUTP * GOUTP; idx += 256) {
            int k = idx / GOUTP, j = idx - k * GOUTP;
            reinterpret_cast<float*>(Wg)[idx] =
                (k < FOUT && j < GOUT) ? Wmn[k * GOUT + j] : 0.f;
        }
        for (int idx = tid; idx < GOUTP; idx += 256)
            bg[idx] = (idx < GOUT) ? bmn[idx] : 0.f;
    }
    __syncthreads();

    const int n = blockIdx.x * 256 + tid;
    if (n >= nNodes) return;

    float4 acc[F4];
    #pragma unroll
    for (int j4 = 0; j4 < F4; j4++) acc[j4] = reinterpret_cast<float4*>(bl)[j4];

    const float* hrow = h + (long long)n * FHP;
    #pragma unroll 1
    for (int k = 0; k < FH; k++) {
        float xk = hrow[k];
        const float4* wrow = &Wl[k * F4];
        #pragma unroll
        for (int j4 = 0; j4 < F4; j4++) fma4(acc[j4], wrow[j4], xk);
    }
    const float* arow = agg + (long long)n * FAGG;
    #pragma unroll 1
    for (int k = 0; k < FAGG; k++) {
        float xk = arow[k];
        const float4* wrow = &Wl[(FH + k) * F4];
        #pragma unroll
        for (int j4 = 0; j4 < F4; j4++) fma4(acc[j4], wrow[j4], xk);
    }

    // relu into acc, write h_next
    #pragma unroll
    for (int j4 = 0; j4 < F4; j4++) {
        acc[j4].x = fmaxf(acc[j4].x, 0.f);
        acc[j4].y = fmaxf(acc[j4].y, 0.f);
        acc[j4].z = fmaxf(acc[j4].z, 0.f);
        acc[j4].w = fmaxf(acc[j4].w, 0.f);
    }
    float4* orow = reinterpret_cast<float4*>(out + (long long)n * FOUTP);
    #pragma unroll
    for (int j4 = 0; j4 < F4; j4++) orow[j4] = acc[j4];

    // fused g for next layer: g = h_next @ Wg + bg
    if constexpr (GOUT > 0) {
        float4 gacc[G4];
        #pragma unroll
        for (int j4 = 0; j4 < G4; j4++) gacc[j4] = reinterpret_cast<float4*>(bg)[j4];
        #pragma unroll 1
        for (int k4 = 0; k4 < F4; ++k4) {
            float4 xv = acc[k4];
            #pragma unroll
            for (int c = 0; c < 4; ++c) {
                float xc = (c == 0) ? xv.x : (c == 1) ? xv.y : (c == 2) ? xv.z : xv.w;
                const float4* wrow = &Wg[(k4 * 4 + c) * G4];
                #pragma unroll
                for (int j4 = 0; j4 < G4; j4++) fma4(gacc[j4], wrow[j4], xc);
            }
        }
        float4* grow = reinterpret_cast<float4*>(gout + (long long)n * GOUTP);
        #pragma unroll
        for (int j4 = 0; j4 < G4; j4++) grow[j4] = gacc[j4];
    }
}

extern "C" void kernel_launch(void* const* d_in, const int* in_sizes, int n_in,
                              void* d_out, int out_size, void* d_ws, size_t ws_size,
                              hipStream_t stream)
{
    const float* nfeats = (const float*)d_in[0];
    const float* efeats = (const float*)d_in[1];
    const int*   src    = (const int*)d_in[2];
    const int*   dst    = (const int*)d_in[3];
    const float* Wm1 = (const float*)d_in[4],  *bm1 = (const float*)d_in[5];
    const float* Wa1 = (const float*)d_in[6],  *ba1 = (const float*)d_in[7];
    const float* Wm2 = (const float*)d_in[8],  *bm2 = (const float*)d_in[9];
    const float* Wa2 = (const float*)d_in[10], *ba2 = (const float*)d_in[11];
    const float* Wm3 = (const float*)d_in[12], *bm3 = (const float*)d_in[13];
    const float* Wa3 = (const float*)d_in[14], *ba3 = (const float*)d_in[15];
    float* out = (float*)d_out;

    constexpr int N = 100000;
    constexpr int E = 3200000;                      // divisible by 512
    constexpr int SCAN_BLOCKS = (N + 1023) / 1024;  // 98

    float* ws   = (float*)d_ws;
    float* h1   = ws;                            // N x 52
    float* h2   = h1 + (size_t)N * 52;           // N x 28
    float* agg  = h2 + (size_t)N * 28;           // N x 52
    float* g    = agg + (size_t)N * 52;          // N x 52 (per-layer stride)
    int* counts = (int*)(g + (size_t)N * 52);    // N
    int* cursor = counts + N;                    // N
    int* bsums  = cursor + N;                    // 128
    int* eidS   = bsums + 128;                   // E
    int* dS     = eidS + E;                      // E
    float* Wp1  = (float*)(dS + E);              // 64 x 52
    float* Wp2  = Wp1 + 64 * 52;                 // 64 x 28
    float* Wp3  = Wp2 + 64 * 28;                 // 64 x 32

    // ---- pack We tables (e-part rows, padded cols) ----
    pack_we<64, 50, 52><<<(64 * 52 + 255) / 256, 256, 0, stream>>>(Wm1, Wp1);
    pack_we<50, 25, 28><<<(64 * 28 + 255) / 256, 256, 0, stream>>>(Wm2, Wp2);
    pack_we<25, 32, 32><<<(64 * 32 + 255) / 256, 256, 0, stream>>>(Wm3, Wp3);

    // ---- CSR build (counting sort by dst) ----
    hipMemsetAsync(counts, 0, (size_t)N * sizeof(int), stream);
    hist_kernel<<<2048, 256, 0, stream>>>(dst, counts, E);
    scan_block<<<SCAN_BLOCKS, 1024, 0, stream>>>(counts, cursor, bsums, N);
    scan_small<<<1, 64, 0, stream>>>(bsums, SCAN_BLOCKS);
    add_offsets<<<SCAN_BLOCKS, 1024, 0, stream>>>(cursor, bsums, N);
    scatter_kernel<<<2048, 256, 0, stream>>>(dst, cursor, eidS, dS, E);

    const int EB = E / 512;          // 512 edges per block
    const int NB = (N + 255) / 256;

    // ---- g1 = nfeats @ Wm1(h-part) + bm1 ----
    gemv_g<64, 50, 52><<<NB, 256, 0, stream>>>(nfeats, Wm1, bm1, g, N);

    // ---- layer 1 ----
    hipMemsetAsync(agg, 0, (size_t)N * 52 * sizeof(float), stream);
    edge_kernel<50, 52, 51><<<EB, 256, 0, stream>>>(g, efeats, src, eidS, dS, Wp1, agg);
    node_kernel<64, 64, 50, 50, 52, 25, 28><<<NB, 256, 0, stream>>>(
        nfeats, agg, Wa1, ba1, Wm2, bm2, h1, g, N);   // writes h1 and g2

    // ---- layer 2 ----
    hipMemsetAsync(agg, 0, (size_t)N * 52 * sizeof(float), stream);
    edge_kernel<25, 28, 25><<<EB, 256, 0, stream>>>(g, efeats, src, eidS, dS, Wp2, agg);
    node_kernel<50, 52, 25, 25, 28, 32, 32><<<NB, 256, 0, stream>>>(
        h1, agg, Wa2, ba2, Wm3, bm3, h2, g, N);       // writes h2 and g3

    // ---- layer 3 ----
    hipMemsetAsync(agg, 0, (size_t)N * 52 * sizeof(float), stream);
    edge_kernel<32, 32, 33><<<EB, 256, 0, stream>>>(g, efeats, src, eidS, dS, Wp3, agg);
    node_kernel<25, 28, 32, 32, 32, 0, 0><<<NB, 256, 0, stream>>>(
        h2, agg, Wa3, ba3, nullptr, nullptr, out, nullptr, N);
}

// Round 10
// 2154.510 us; speedup vs baseline: 13.3578x; 1.0072x over previous
//
#include <hip/hip_runtime.h>

#define DEVINL __device__ __forceinline__

DEVINL void fma4(float4& a, const float4 w, const float x) {
    a.x += w.x * x; a.y += w.y * x; a.z += w.z * x; a.w += w.w * x;
}

// pack two fp32 into one u32 of 2 bf16 (RNE); element "lo" in low half
DEVINL unsigned bfpair(float lo, float hi) {
    unsigned a = __float_as_uint(lo);
    a += 0x7FFFu + ((a >> 16) & 1u);
    unsigned b = __float_as_uint(hi);
    b += 0x7FFFu + ((b >> 16) & 1u);
    return (a >> 16) | (b & 0xFFFF0000u);
}

// ===========================================================================
// CSR build: counting sort of edges by dst.  (unchanged, proven)
// ===========================================================================
__global__ __launch_bounds__(256) void hist_kernel(const int* __restrict__ d,
                                                   int* __restrict__ counts, int n) {
    for (int i = blockIdx.x * 256 + threadIdx.x; i < n; i += gridDim.x * 256)
        atomicAdd(&counts[d[i]], 1);
}

__global__ __launch_bounds__(1024) void scan_block(const int* __restrict__ in,
                                                   int* __restrict__ out,
                                                   int* __restrict__ bsums, int n) {
    __shared__ int buf[2][1024];
    const int t = threadIdx.x;
    const int i = blockIdx.x * 1024 + t;
    const int v = (i < n) ? in[i] : 0;
    int cur = 0;
    buf[0][t] = v;
    __syncthreads();
    #pragma unroll
    for (int s = 1; s < 1024; s <<= 1) {
        int x = buf[cur][t];
        if (t >= s) x += buf[cur][t - s];
        buf[cur ^ 1][t] = x;
        cur ^= 1;
        __syncthreads();
    }
    if (i < n) out[i] = buf[cur][t] - v;            // exclusive
    if (t == 1023) bsums[blockIdx.x] = buf[cur][t]; // block total
}

__global__ void scan_small(int* __restrict__ bs, int nb) {
    if (blockIdx.x == 0 && threadIdx.x == 0) {
        int acc = 0;
        for (int i = 0; i < nb; i++) { int v = bs[i]; bs[i] = acc; acc += v; }
    }
}

__global__ __launch_bounds__(1024) void add_offsets(int* __restrict__ out,
                                                    const int* __restrict__ bs, int n) {
    int i = blockIdx.x * 1024 + threadIdx.x;
    if (i < n) out[i] += bs[blockIdx.x];
}

__global__ __launch_bounds__(256) void scatter_kernel(const int* __restrict__ d,
                                                      int* __restrict__ cursor,
                                                      int* __restrict__ eidS,
                                                      int* __restrict__ dS, int n) {
    for (int i = blockIdx.x * 256 + threadIdx.x; i < n; i += gridDim.x * 256) {
        int dd = d[i];
        int pos = atomicAdd(&cursor[dd], 1);
        eidS[pos] = i;
        dS[pos] = dd;
    }
}

// ===========================================================================
// permute_convert (gather-style): ebf[p] = bf16(efeats[eidS[p]]).
// Random 256B row reads (paid ONCE), perfectly sequential 128B row writes.
// ===========================================================================
__global__ __launch_bounds__(256) void permute_convert(
    const float* __restrict__ ef, const int* __restrict__ eidS,
    unsigned* __restrict__ ebf)
{
    const long long p = (long long)blockIdx.x * 256 + threadIdx.x;
    const int eid = eidS[p];
    const float4* in = reinterpret_cast<const float4*>(ef + (long long)eid * 64);
    uint4* outp = reinterpret_cast<uint4*>(ebf + p * 32);
    #pragma unroll
    for (int q = 0; q < 8; ++q) {
        float4 a = in[2 * q], c = in[2 * q + 1];
        uint4 o;
        o.x = bfpair(a.x, a.y); o.y = bfpair(a.z, a.w);
        o.z = bfpair(c.x, c.y); o.w = bfpair(c.z, c.w);
        outp[q] = o;
    }
}

// ===========================================================================
// pack_we: e-part of Wm (rows [FIN, FIN+64)) -> padded [64][FOUTP] table.
// ===========================================================================
template<int FIN, int FOUT, int FOUTP>
__global__ __launch_bounds__(256) void pack_we(const float* __restrict__ W,
                                               float* __restrict__ Wp) {
    int idx = blockIdx.x * 256 + threadIdx.x;
    if (idx >= 64 * FOUTP) return;
    int k = idx / FOUTP, j = idx - k * FOUTP;
    Wp[idx] = (j < FOUT) ? W[(FIN + k) * FOUT + j] : 0.f;
}

// ===========================================================================
// gemv_g: g = x @ W(h-part rows [0,FIN)) + b, padded to FOUTP.
// ===========================================================================
template<int FIN, int FOUT, int FOUTP>
__global__ __launch_bounds__(256) void gemv_g(
    const float* __restrict__ x,
    const float* __restrict__ W,
    const float* __restrict__ b,
    float* __restrict__ g, int nNodes)
{
    constexpr int F4 = FOUTP / 4;
    __shared__ float4 Wl[FIN * F4];
    __shared__ float  bl[FOUTP];
    const int tid = threadIdx.x;
    for (int idx = tid; idx < FIN * FOUTP; idx += 256) {
        int k = idx / FOUTP, j = idx - k * FOUTP;
        reinterpret_cast<float*>(Wl)[idx] = (j < FOUT) ? W[k * FOUT + j] : 0.f;
    }
    for (int idx = tid; idx < FOUTP; idx += 256)
        bl[idx] = (idx < FOUT) ? b[idx] : 0.f;
    __syncthreads();
    const int n = blockIdx.x * 256 + tid;
    if (n >= nNodes) return;
    float4 acc[F4];
    #pragma unroll
    for (int j4 = 0; j4 < F4; j4++) acc[j4] = reinterpret_cast<float4*>(bl)[j4];
    const float* xr = x + (long long)n * FIN;
    #pragma unroll 1
    for (int k = 0; k < FIN; ++k) {
        float xk = xr[k];
        const float4* wrow = &Wl[k * F4];
        #pragma unroll
        for (int j4 = 0; j4 < F4; j4++) fma4(acc[j4], wrow[j4], xk);
    }
    float4* gr = reinterpret_cast<float4*>(g + (long long)n * FOUTP);
    #pragma unroll
    for (int j4 = 0; j4 < F4; j4++) gr[j4] = acc[j4];
}

// ===========================================================================
// PRIMARY edge kernel: m = relu(g[src] + e @ We), e-rows from the permuted
// bf16 stream (sequential). 2 edges/thread, 512 edges/block.
// Staging: 2 chunks of 16 u32 per row into thread-PRIVATE LDS slots
// (stride 17; max index 511*17+15 = 8702 < 8704 -- the round-9 OOB fixed).
// No stage barriers (private slots). W rows via wave-uniform global loads.
// Epilogue: segmented reduce by sorted dst, ~1 atomic per (segment,feature).
// ===========================================================================
template<int FOUT, int FOUTP, int MS>
__global__ __launch_bounds__(256) void edge_bf16(
    const float* __restrict__ g,      // [N][FOUTP] = h@Wh + b
    const unsigned* __restrict__ ebf, // [E][32] u32 bf16-pairs, sorted order
    const int* __restrict__ src,
    const int* __restrict__ eidS,     // sorted -> original edge id
    const int* __restrict__ dS,       // dst in sorted order
    const float* __restrict__ Wp,     // packed [64][FOUTP] e-part
    float* __restrict__ agg)
{
    constexpr int F4 = FOUTP / 4;
    constexpr int ST = 17;            // u32 stride per staged half-row (odd)
    static_assert(128 * MS + 64 <= 512 * ST, "msg buf exceeds sbuf");

    __shared__ unsigned su[512 * ST]; // union: staged bf16 chunks / msg floats
    __shared__ int dseg[512];

    const int tid = threadIdx.x;
    const long long pb = (long long)blockIdx.x * 512;
    dseg[tid]       = dS[pb + tid];
    dseg[tid + 256] = dS[pb + 256 + tid];
    const int eid0 = eidS[pb + tid];
    const int eid1 = eidS[pb + 256 + tid];
    const int s0 = src[eid0];
    const int s1 = src[eid1];

    // g-gather straight into accumulators (L2/L3-resident table)
    float4 acc0[F4], acc1[F4];
    {
        const float4* g0 = reinterpret_cast<const float4*>(g + (long long)s0 * FOUTP);
        const float4* g1 = reinterpret_cast<const float4*>(g + (long long)s1 * FOUTP);
        #pragma unroll
        for (int j = 0; j < F4; j++) acc0[j] = g0[j];
        #pragma unroll
        for (int j = 0; j < F4; j++) acc1[j] = g1[j];
    }

    const int t0 = tid * ST, t1 = (tid + 256) * ST;
    const uint4* e0 = reinterpret_cast<const uint4*>(ebf + (unsigned long long)(pb + tid) * 32);
    const uint4* e1 = reinterpret_cast<const uint4*>(ebf + (unsigned long long)(pb + 256 + tid) * 32);
    const float4* Wp4 = reinterpret_cast<const float4*>(Wp);

    // 2 chunks x (stage 16 u32/row, consume 32 k-steps). No stage barriers:
    // slots are thread-private; in-thread ds ordering is guaranteed.
    for (int c = 0; c < 2; ++c) {
        {
            uint4 r[4];
            #pragma unroll
            for (int q = 0; q < 4; q++) r[q] = e0[4 * c + q];
            #pragma unroll
            for (int q = 0; q < 4; q++) {
                su[t0 + 4 * q] = r[q].x; su[t0 + 4 * q + 1] = r[q].y;
                su[t0 + 4 * q + 2] = r[q].z; su[t0 + 4 * q + 3] = r[q].w;
            }
            #pragma unroll
            for (int q = 0; q < 4; q++) r[q] = e1[4 * c + q];
            #pragma unroll
            for (int q = 0; q < 4; q++) {
                su[t1 + 4 * q] = r[q].x; su[t1 + 4 * q + 1] = r[q].y;
                su[t1 + 4 * q + 2] = r[q].z; su[t1 + 4 * q + 3] = r[q].w;
            }
        }
        // consume: u32 index kp in chunk => k-steps 32c+2kp and 32c+2kp+1
        #pragma unroll 1
        for (int kp = 0; kp < 16; ++kp) {
            const unsigned u0 = su[t0 + kp];
            const unsigned u1 = su[t1 + kp];
            const float x0e = __uint_as_float(u0 << 16);
            const float x0o = __uint_as_float(u0 & 0xFFFF0000u);
            const float x1e = __uint_as_float(u1 << 16);
            const float x1o = __uint_as_float(u1 & 0xFFFF0000u);
            const int kbase = 32 * c + 2 * kp;
            const float4* w0 = &Wp4[kbase * F4];
            const float4* w1 = &Wp4[(kbase + 1) * F4];
            #pragma unroll
            for (int j = 0; j < F4; j++) { float4 w = w0[j]; fma4(acc0[j], w, x0e); fma4(acc1[j], w, x1e); }
            #pragma unroll
            for (int j = 0; j < F4; j++) { float4 w = w1[j]; fma4(acc0[j], w, x0o); fma4(acc1[j], w, x1o); }
        }
    }

    // ---- epilogue: 4 batches of 128 messages, segmented reduce by dst ----
    float* msg = reinterpret_cast<float*>(su);
    const int lane = tid & 63;
    const int wv   = tid >> 6;

    #pragma unroll 1
    for (int bb = 0; bb < 4; ++bb) {
        __syncthreads();   // consume done / prev batch reads done
        if ((tid >> 7) == (bb & 1)) {
            const int r = tid & 127;
            float* mrow = &msg[r * MS];
            if (bb < 2) {
                #pragma unroll
                for (int j4 = 0; j4 < F4; j4++) {
                    if (4 * j4 + 0 < FOUT) mrow[4 * j4 + 0] = fmaxf(acc0[j4].x, 0.f);
                    if (4 * j4 + 1 < FOUT) mrow[4 * j4 + 1] = fmaxf(acc0[j4].y, 0.f);
                    if (4 * j4 + 2 < FOUT) mrow[4 * j4 + 2] = fmaxf(acc0[j4].z, 0.f);
                    if (4 * j4 + 3 < FOUT) mrow[4 * j4 + 3] = fmaxf(acc0[j4].w, 0.f);
                }
            } else {
                #pragma unroll
                for (int j4 = 0; j4 < F4; j4++) {
                    if (4 * j4 + 0 < FOUT) mrow[4 * j4 + 0] = fmaxf(acc1[j4].x, 0.f);
                    if (4 * j4 + 1 < FOUT) mrow[4 * j4 + 1] = fmaxf(acc1[j4].y, 0.f);
                    if (4 * j4 + 2 < FOUT) mrow[4 * j4 + 2] = fmaxf(acc1[j4].z, 0.f);
                    if (4 * j4 + 3 < FOUT) mrow[4 * j4 + 3] = fmaxf(acc1[j4].w, 0.f);
                }
            }
        }
        __syncthreads();

        const int rbase = bb * 128;
        for (int r0 = wv * 32; r0 < wv * 32 + 32; ++r0) {
            int dr = dseg[rbase + r0];
            if (r0 > 0 && dseg[rbase + r0 - 1] == dr) continue;
            float s = 0.f;
            int rr = r0;
            while (true) {
                s += msg[rr * MS + lane];
                ++rr;
                if (rr >= 128 || dseg[rbase + rr] != dr) break;
            }
            if (lane < FOUT) atomicAdd(agg + (long long)dr * FOUT + lane, s);
        }
    }
}

// ===========================================================================
// FALLBACK edge kernel (ws too small for ebf): round-8 proven structure,
// fp32 efeats gather, stage barriers removed (private slots need none).
// ===========================================================================
template<int FOUT, int FOUTP, int MS>
__global__ __launch_bounds__(256) void edge_fb(
    const float* __restrict__ g,
    const float* __restrict__ efeats,
    const int* __restrict__ src,
    const int* __restrict__ eidS,
    const int* __restrict__ dS,
    const float* __restrict__ Wp,
    float* __restrict__ agg)
{
    constexpr int F4 = FOUTP / 4;
    constexpr int ST = 17;
    static_assert(128 * MS + 64 <= 512 * ST, "msg buf exceeds sbuf");

    __shared__ float sbuf[512 * ST];
    __shared__ int   dseg[512];

    const int tid = threadIdx.x;
    const long long pb = (long long)blockIdx.x * 512;
    dseg[tid]       = dS[pb + tid];
    dseg[tid + 256] = dS[pb + 256 + tid];

    const int eid0 = eidS[pb + tid], eid1 = eidS[pb + 256 + tid];
    const int s0 = src[eid0], s1 = src[eid1];
    const float4* gr0 = reinterpret_cast<const float4*>(g + (long long)s0 * FOUTP);
    const float4* gr1 = reinterpret_cast<const float4*>(g + (long long)s1 * FOUTP);
    const float*  er0 = efeats + (long long)eid0 * 64;
    const float*  er1 = efeats + (long long)eid1 * 64;
    const float4* Wp4 = reinterpret_cast<const float4*>(Wp);

    float4 acc0[F4], acc1[F4];
    #pragma unroll
    for (int j4 = 0; j4 < F4; j4++) acc0[j4] = gr0[j4];
    #pragma unroll
    for (int j4 = 0; j4 < F4; j4++) acc1[j4] = gr1[j4];

    const int t0 = tid * ST;
    const int t1 = (tid + 256) * ST;

    for (int c = 0; c < 4; ++c) {
        const int off = c * 16;
        #pragma unroll
        for (int f = 0; f < 4; ++f) {
            float4 v0 = *reinterpret_cast<const float4*>(er0 + off + 4 * f);
            float4 v1 = *reinterpret_cast<const float4*>(er1 + off + 4 * f);
            float* d0 = &sbuf[t0 + 4 * f];
            float* d1 = &sbuf[t1 + 4 * f];
            d0[0] = v0.x; d0[1] = v0.y; d0[2] = v0.z; d0[3] = v0.w;
            d1[0] = v1.x; d1[1] = v1.y; d1[2] = v1.z; d1[3] = v1.w;
        }
        // no barrier: slots are thread-private
        #pragma unroll 1
        for (int k = 0; k < 16; ++k) {
            const float x0 = sbuf[t0 + k];
            const float x1 = sbuf[t1 + k];
            const float4* wrow = &Wp4[(off + k) * F4];
            #pragma unroll
            for (int j4 = 0; j4 < F4; j4++) {
                float4 w = wrow[j4];
                fma4(acc0[j4], w, x0);
                fma4(acc1[j4], w, x1);
            }
        }
    }

    const int lane = tid & 63;
    const int wv   = tid >> 6;

    #pragma unroll 1
    for (int bb = 0; bb < 4; ++bb) {
        __syncthreads();
        if ((tid >> 7) == (bb & 1)) {
            const int r = tid & 127;
            float* mrow = &sbuf[r * MS];
            if (bb < 2) {
                #pragma unroll
                for (int j4 = 0; j4 < F4; j4++) {
                    if (4 * j4 + 0 < FOUT) mrow[4 * j4 + 0] = fmaxf(acc0[j4].x, 0.f);
                    if (4 * j4 + 1 < FOUT) mrow[4 * j4 + 1] = fmaxf(acc0[j4].y, 0.f);
                    if (4 * j4 + 2 < FOUT) mrow[4 * j4 + 2] = fmaxf(acc0[j4].z, 0.f);
                    if (4 * j4 + 3 < FOUT) mrow[4 * j4 + 3] = fmaxf(acc0[j4].w, 0.f);
                }
            } else {
                #pragma unroll
                for (int j4 = 0; j4 < F4; j4++) {
                    if (4 * j4 + 0 < FOUT) mrow[4 * j4 + 0] = fmaxf(acc1[j4].x, 0.f);
                    if (4 * j4 + 1 < FOUT) mrow[4 * j4 + 1] = fmaxf(acc1[j4].y, 0.f);
                    if (4 * j4 + 2 < FOUT) mrow[4 * j4 + 2] = fmaxf(acc1[j4].z, 0.f);
                    if (4 * j4 + 3 < FOUT) mrow[4 * j4 + 3] = fmaxf(acc1[j4].w, 0.f);
                }
            }
        }
        __syncthreads();

        const int rbase = bb * 128;
        for (int r0 = wv * 32; r0 < wv * 32 + 32; ++r0) {
            int dr = dseg[rbase + r0];
            if (r0 > 0 && dseg[rbase + r0 - 1] == dr) continue;
            float s = 0.f;
            int rr = r0;
            while (true) {
                s += sbuf[rr * MS + lane];
                ++rr;
                if (rr >= 128 || dseg[rbase + rr] != dr) break;
            }
            if (lane < FOUT) atomicAdd(agg + (long long)dr * FOUT + lane, s);
        }
    }
}

// ===========================================================================
// Node kernel (fused): h_next = relu(cat(h, agg) @ Wa + ba), plus fused
// g_next = h_next @ Wm_next(h-part) + bm_next when GOUT > 0.
// ===========================================================================
template<int FH, int FHP, int FAGG, int FOUT, int FOUTP, int GOUT, int GOUTP>
__global__ __launch_bounds__(256) void node_kernel(
    const float* __restrict__ h,
    const float* __restrict__ agg,
    const float* __restrict__ Wa,
    const float* __restrict__ ba,
    const float* __restrict__ Wmn,
    const float* __restrict__ bmn,
    float* __restrict__ out,
    float* __restrict__ gout,
    int nNodes)
{
    constexpr int K  = FH + FAGG;
    constexpr int F4 = FOUTP / 4;
    constexpr int G4 = (GOUT > 0) ? GOUTP / 4 : 1;

    __shared__ float4 Wl[K * F4];
    __shared__ float4 Wg[(GOUT > 0) ? FOUTP * G4 : 1];
    __shared__ float  bl[FOUTP];
    __shared__ float  bg[(GOUT > 0) ? GOUTP : 4];

    const int tid = threadIdx.x;
    for (int idx = tid; idx < K * FOUTP; idx += 256) {
        int k = idx / FOUTP, j = idx - k * FOUTP;
        reinterpret_cast<float*>(Wl)[idx] = (j < FOUT) ? Wa[k * FOUT + j] : 0.f;
    }
    for (int idx = tid; idx < FOUTP; idx += 256)
        bl[idx] = (idx < FOUT) ? ba[idx] : 0.f;
    if constexpr (GOUT > 0) {
        for (int idx = tid; idx < FOUTP * GOUTP; idx += 256) {
            int k = idx / GOUTP, j = idx - k * GOUTP;
            reinterpret_cast<float*>(Wg)[idx] =
                (k < FOUT && j < GOUT) ? Wmn[k * GOUT + j] : 0.f;
        }
        for (int idx = tid; idx < GOUTP; idx += 256)
            bg[idx] = (idx < GOUT) ? bmn[idx] : 0.f;
    }
    __syncthreads();

    const int n = blockIdx.x * 256 + tid;
    if (n >= nNodes) return;

    float4 acc[F4];
    #pragma unroll
    for (int j4 = 0; j4 < F4; j4++) acc[j4] = reinterpret_cast<float4*>(bl)[j4];

    const float* hrow = h + (long long)n * FHP;
    #pragma unroll 1
    for (int k = 0; k < FH; k++) {
        float xk = hrow[k];
        const float4* wrow = &Wl[k * F4];
        #pragma unroll
        for (int j4 = 0; j4 < F4; j4++) fma4(acc[j4], wrow[j4], xk);
    }
    const float* arow = agg + (long long)n * FAGG;
    #pragma unroll 1
    for (int k = 0; k < FAGG; k++) {
        float xk = arow[k];
        const float4* wrow = &Wl[(FH + k) * F4];
        #pragma unroll
        for (int j4 = 0; j4 < F4; j4++) fma4(acc[j4], wrow[j4], xk);
    }

    #pragma unroll
    for (int j4 = 0; j4 < F4; j4++) {
        acc[j4].x = fmaxf(acc[j4].x, 0.f);
        acc[j4].y = fmaxf(acc[j4].y, 0.f);
        acc[j4].z = fmaxf(acc[j4].z, 0.f);
        acc[j4].w = fmaxf(acc[j4].w, 0.f);
    }
    float4* orow = reinterpret_cast<float4*>(out + (long long)n * FOUTP);
    #pragma unroll
    for (int j4 = 0; j4 < F4; j4++) orow[j4] = acc[j4];

    if constexpr (GOUT > 0) {
        float4 gacc[G4];
        #pragma unroll
        for (int j4 = 0; j4 < G4; j4++) gacc[j4] = reinterpret_cast<float4*>(bg)[j4];
        #pragma unroll 1
        for (int k4 = 0; k4 < F4; ++k4) {
            float4 xv = acc[k4];
            #pragma unroll
            for (int c = 0; c < 4; ++c) {
                float xc = (c == 0) ? xv.x : (c == 1) ? xv.y : (c == 2) ? xv.z : xv.w;
                const float4* wrow = &Wg[(k4 * 4 + c) * G4];
                #pragma unroll
                for (int j4 = 0; j4 < G4; j4++) fma4(gacc[j4], wrow[j4], xc);
            }
        }
        float4* grow = reinterpret_cast<float4*>(gout + (long long)n * GOUTP);
        #pragma unroll
        for (int j4 = 0; j4 < G4; j4++) grow[j4] = gacc[j4];
    }
}

extern "C" void kernel_launch(void* const* d_in, const int* in_sizes, int n_in,
                              void* d_out, int out_size, void* d_ws, size_t ws_size,
                              hipStream_t stream)
{
    const float* nfeats = (const float*)d_in[0];
    const float* efeats = (const float*)d_in[1];
    const int*   src    = (const int*)d_in[2];
    const int*   dst    = (const int*)d_in[3];
    const float* Wm1 = (const float*)d_in[4],  *bm1 = (const float*)d_in[5];
    const float* Wa1 = (const float*)d_in[6],  *ba1 = (const float*)d_in[7];
    const float* Wm2 = (const float*)d_in[8],  *bm2 = (const float*)d_in[9];
    const float* Wa2 = (const float*)d_in[10], *ba2 = (const float*)d_in[11];
    const float* Wm3 = (const float*)d_in[12], *bm3 = (const float*)d_in[13];
    const float* Wa3 = (const float*)d_in[14], *ba3 = (const float*)d_in[15];
    float* out = (float*)d_out;

    constexpr int N = 100000;
    constexpr int E = 3200000;                      // % 512 == 0
    constexpr int SCAN_BLOCKS = (N + 1023) / 1024;  // 98

    // ---- base layout: EXACTLY the round-8 proven footprint (~100 MB) ----
    float* ws   = (float*)d_ws;
    float* h1   = ws;                            // N x 52
    float* h2   = h1 + (size_t)N * 52;           // N x 28
    float* agg  = h2 + (size_t)N * 28;           // N x 52
    float* g    = agg + (size_t)N * 52;          // N x 52
    int* counts = (int*)(g + (size_t)N * 52);    // N
    int* cursor = counts + N;                    // N
    int* bsums  = cursor + N;                    // 128
    int* eidS   = bsums + 128;                   // E
    int* dS     = eidS + E;                      // E
    float* Wp1  = (float*)(dS + E);              // 64 x 52
    float* Wp2  = Wp1 + 64 * 52;                 // 64 x 28
    float* Wp3  = Wp2 + 64 * 28;                 // 64 x 32
    float* endp = Wp3 + 64 * 32;

    size_t usedB   = (size_t)((char*)endp - (char*)d_ws);
    size_t ebfOffB = (usedB + 127) & ~(size_t)127;
    size_t neededB = ebfOffB + (size_t)E * 128;  // + E x 32 u32 bf16 rows
    const bool useBf = (ws_size >= neededB);
    unsigned* ebf = (unsigned*)((char*)d_ws + ebfOffB);

    // ---- pack We tables ----
    pack_we<64, 50, 52><<<(64 * 52 + 255) / 256, 256, 0, stream>>>(Wm1, Wp1);
    pack_we<50, 25, 28><<<(64 * 28 + 255) / 256, 256, 0, stream>>>(Wm2, Wp2);
    pack_we<25, 32, 32><<<(64 * 32 + 255) / 256, 256, 0, stream>>>(Wm3, Wp3);

    // ---- CSR build (counting sort by dst) ----
    hipMemsetAsync(counts, 0, (size_t)N * sizeof(int), stream);
    hist_kernel<<<2048, 256, 0, stream>>>(dst, counts, E);
    scan_block<<<SCAN_BLOCKS, 1024, 0, stream>>>(counts, cursor, bsums, N);
    scan_small<<<1, 64, 0, stream>>>(bsums, SCAN_BLOCKS);
    add_offsets<<<SCAN_BLOCKS, 1024, 0, stream>>>(cursor, bsums, N);
    scatter_kernel<<<2048, 256, 0, stream>>>(dst, cursor, eidS, dS, E);

    // ---- one-time gather + bf16 convert of efeats into sorted order ----
    if (useBf)
        permute_convert<<<E / 256, 256, 0, stream>>>(efeats, eidS, ebf);

    const int EB = E / 512;
    const int NB = (N + 255) / 256;

    // ---- g1 = nfeats @ Wm1(h-part) + bm1 ----
    gemv_g<64, 50, 52><<<NB, 256, 0, stream>>>(nfeats, Wm1, bm1, g, N);

    // ---- layer 1 ----
    hipMemsetAsync(agg, 0, (size_t)N * 52 * sizeof(float), stream);
    if (useBf)
        edge_bf16<50, 52, 51><<<EB, 256, 0, stream>>>(g, ebf, src, eidS, dS, Wp1, agg);
    else
        edge_fb<50, 52, 51><<<EB, 256, 0, stream>>>(g, efeats, src, eidS, dS, Wp1, agg);
    node_kernel<64, 64, 50, 50, 52, 25, 28><<<NB, 256, 0, stream>>>(
        nfeats, agg, Wa1, ba1, Wm2, bm2, h1, g, N);

    // ---- layer 2 ----
    hipMemsetAsync(agg, 0, (size_t)N * 52 * sizeof(float), stream);
    if (useBf)
        edge_bf16<25, 28, 25><<<EB, 256, 0, stream>>>(g, ebf, src, eidS, dS, Wp2, agg);
    else
        edge_fb<25, 28, 25><<<EB, 256, 0, stream>>>(g, efeats, src, eidS, dS, Wp2, agg);
    node_kernel<50, 52, 25, 25, 28, 32, 32><<<NB, 256, 0, stream>>>(
        h1, agg, Wa2, ba2, Wm3, bm3, h2, g, N);

    // ---- layer 3 ----
    hipMemsetAsync(agg, 0, (size_t)N * 52 * sizeof(float), stream);
    if (useBf)
        edge_bf16<32, 32, 33><<<EB, 256, 0, stream>>>(g, ebf, src, eidS, dS, Wp3, agg);
    else
        edge_fb<32, 32, 33><<<EB, 256, 0, stream>>>(g, efeats, src, eidS, dS, Wp3, agg);
    node_kernel<25, 28, 32, 32, 32, 0, 0><<<NB, 256, 0, stream>>>(
        h2, agg, Wa3, ba3, nullptr, nullptr, out, nullptr, N);
}

// Round 11
// 1776.309 us; speedup vs baseline: 16.2018x; 1.2129x over previous
//
#include <hip/hip_runtime.h>

#define DEVINL __device__ __forceinline__

typedef __attribute__((ext_vector_type(8))) short bf16x8;
typedef __attribute__((ext_vector_type(4))) float f32x4;

DEVINL void fma4(float4& a, const float4 w, const float x) {
    a.x += w.x * x; a.y += w.y * x; a.z += w.z * x; a.w += w.w * x;
}

DEVINL unsigned short bf16of(float x) {
    unsigned a = __float_as_uint(x);
    a += 0x7FFFu + ((a >> 16) & 1u);
    return (unsigned short)(a >> 16);
}

// pack two fp32 into one u32 of 2 bf16 (RNE); element "lo" in low half
DEVINL unsigned bfpair(float lo, float hi) {
    unsigned a = __float_as_uint(lo);
    a += 0x7FFFu + ((a >> 16) & 1u);
    unsigned b = __float_as_uint(hi);
    b += 0x7FFFu + ((b >> 16) & 1u);
    return (a >> 16) | (b & 0xFFFF0000u);
}

// ===========================================================================
// CSR build: counting sort of edges by dst.  (unchanged, proven)
// ===========================================================================
__global__ __launch_bounds__(256) void hist_kernel(const int* __restrict__ d,
                                                   int* __restrict__ counts, int n) {
    for (int i = blockIdx.x * 256 + threadIdx.x; i < n; i += gridDim.x * 256)
        atomicAdd(&counts[d[i]], 1);
}

__global__ __launch_bounds__(1024) void scan_block(const int* __restrict__ in,
                                                   int* __restrict__ out,
                                                   int* __restrict__ bsums, int n) {
    __shared__ int buf[2][1024];
    const int t = threadIdx.x;
    const int i = blockIdx.x * 1024 + t;
    const int v = (i < n) ? in[i] : 0;
    int cur = 0;
    buf[0][t] = v;
    __syncthreads();
    #pragma unroll
    for (int s = 1; s < 1024; s <<= 1) {
        int x = buf[cur][t];
        if (t >= s) x += buf[cur][t - s];
        buf[cur ^ 1][t] = x;
        cur ^= 1;
        __syncthreads();
    }
    if (i < n) out[i] = buf[cur][t] - v;            // exclusive
    if (t == 1023) bsums[blockIdx.x] = buf[cur][t]; // block total
}

__global__ void scan_small(int* __restrict__ bs, int nb) {
    if (blockIdx.x == 0 && threadIdx.x == 0) {
        int acc = 0;
        for (int i = 0; i < nb; i++) { int v = bs[i]; bs[i] = acc; acc += v; }
    }
}

__global__ __launch_bounds__(1024) void add_offsets(int* __restrict__ out,
                                                    const int* __restrict__ bs, int n) {
    int i = blockIdx.x * 1024 + threadIdx.x;
    if (i < n) out[i] += bs[blockIdx.x];
}

__global__ __launch_bounds__(256) void scatter_kernel(const int* __restrict__ d,
                                                      int* __restrict__ cursor,
                                                      int* __restrict__ eidS,
                                                      int* __restrict__ dS, int n) {
    for (int i = blockIdx.x * 256 + threadIdx.x; i < n; i += gridDim.x * 256) {
        int dd = d[i];
        int pos = atomicAdd(&cursor[dd], 1);
        eidS[pos] = i;
        dS[pos] = dd;
    }
}

// ===========================================================================
// permute_convert: ebf[p] = bf16(efeats[eidS[p]]). Randomness paid ONCE.
// ===========================================================================
__global__ __launch_bounds__(256) void permute_convert(
    const float* __restrict__ ef, const int* __restrict__ eidS,
    unsigned* __restrict__ ebf)
{
    const long long p = (long long)blockIdx.x * 256 + threadIdx.x;
    const int eid = eidS[p];
    const float4* in = reinterpret_cast<const float4*>(ef + (long long)eid * 64);
    uint4* outp = reinterpret_cast<uint4*>(ebf + p * 32);
    #pragma unroll
    for (int q = 0; q < 8; ++q) {
        float4 a = in[2 * q], c = in[2 * q + 1];
        uint4 o;
        o.x = bfpair(a.x, a.y); o.y = bfpair(a.z, a.w);
        o.z = bfpair(c.x, c.y); o.w = bfpair(c.z, c.w);
        outp[q] = o;
    }
}

// ===========================================================================
// pack_we (fp32, fallback path): e-part rows -> padded [64][FOUTP].
// ===========================================================================
template<int FIN, int FOUT, int FOUTP>
__global__ __launch_bounds__(256) void pack_we(const float* __restrict__ W,
                                               float* __restrict__ Wp) {
    int idx = blockIdx.x * 256 + threadIdx.x;
    if (idx >= 64 * FOUTP) return;
    int k = idx / FOUTP, j = idx - k * FOUTP;
    Wp[idx] = (j < FOUT) ? W[(FIN + k) * FOUT + j] : 0.f;
}

// ===========================================================================
// pack_wbt: e-part of Wm -> bf16 TRANSPOSED table WbT[col][64], col padded
// to NT*16 with zeros. Row stride 64 bf16 = 128B (16B-aligned frag loads).
// ===========================================================================
template<int FIN, int FOUT, int NC>
__global__ __launch_bounds__(256) void pack_wbt(const float* __restrict__ W,
                                                unsigned short* __restrict__ WbT) {
    int idx = blockIdx.x * 256 + threadIdx.x;
    if (idx >= NC * 64) return;
    int c = idx / 64, k = idx - c * 64;
    WbT[idx] = (c < FOUT) ? bf16of(W[(FIN + k) * FOUT + c]) : (unsigned short)0;
}

// ===========================================================================
// gemv_g: g = x @ W(h-part rows [0,FIN)) + b, padded to FOUTP.
// ===========================================================================
template<int FIN, int FOUT, int FOUTP>
__global__ __launch_bounds__(256) void gemv_g(
    const float* __restrict__ x,
    const float* __restrict__ W,
    const float* __restrict__ b,
    float* __restrict__ g, int nNodes)
{
    constexpr int F4 = FOUTP / 4;
    __shared__ float4 Wl[FIN * F4];
    __shared__ float  bl[FOUTP];
    const int tid = threadIdx.x;
    for (int idx = tid; idx < FIN * FOUTP; idx += 256) {
        int k = idx / FOUTP, j = idx - k * FOUTP;
        reinterpret_cast<float*>(Wl)[idx] = (j < FOUT) ? W[k * FOUT + j] : 0.f;
    }
    for (int idx = tid; idx < FOUTP; idx += 256)
        bl[idx] = (idx < FOUT) ? b[idx] : 0.f;
    __syncthreads();
    const int n = blockIdx.x * 256 + tid;
    if (n >= nNodes) return;
    float4 acc[F4];
    #pragma unroll
    for (int j4 = 0; j4 < F4; j4++) acc[j4] = reinterpret_cast<float4*>(bl)[j4];
    const float* xr = x + (long long)n * FIN;
    #pragma unroll 1
    for (int k = 0; k < FIN; ++k) {
        float xk = xr[k];
        const float4* wrow = &Wl[k * F4];
        #pragma unroll
        for (int j4 = 0; j4 < F4; j4++) fma4(acc[j4], wrow[j4], xk);
    }
    float4* gr = reinterpret_cast<float4*>(g + (long long)n * FOUTP);
    #pragma unroll
    for (int j4 = 0; j4 < F4; j4++) gr[j4] = acc[j4];
}

// ===========================================================================
// PRIMARY edge kernel (MFMA): m = relu(g[src] + e @ We).
//   512 edges/block, 4 waves; wave wv owns edges [wv*128, wv*128+128).
//   B = We bf16 transposed, loaded ONCE into 8 frags (32 VGPR) -> no per-k
//   W traffic. A = 16-edge rows direct from the sequential bf16 stream.
//   mfma_f32_16x16x32_bf16: A lane: row=l&15, k=(l>>4)*8+j;
//   B lane: col=l&15, k=(l>>4)*8+j; D lane: col=l&15, row=(l>>4)*4+reg
//   (C/D layout HW-verified per guide §3).
//   Epilogue per 32-row chunk: D + g[src] (gathered), relu, wave-private LDS
//   msg tile, segmented reduce by sorted dst (NO barriers in main loop; all
//   LDS msg traffic is same-wave).
// ===========================================================================
template<int FOUT, int FOUTP, int NT>
__global__ __launch_bounds__(256) void edge_mfma(
    const float* __restrict__ g,      // [N][FOUTP]
    const unsigned* __restrict__ ebf, // [E][32] u32 = 64 bf16, sorted order
    const int* __restrict__ src,
    const int* __restrict__ eidS,
    const int* __restrict__ dS,
    const unsigned short* __restrict__ WbT, // [NT*16][64] bf16 transposed
    float* __restrict__ agg)
{
    constexpr int MS = NT * 16 + 1;

    __shared__ float msg[4][32 * MS];   // wave-private 32-row tiles
    __shared__ int sIdxL[512];
    __shared__ int dseg[512];

    const int tid = threadIdx.x;
    const long long pb = (long long)blockIdx.x * 512;
    {
        int e0 = eidS[pb + tid], e1 = eidS[pb + 256 + tid];
        sIdxL[tid] = src[e0];
        sIdxL[tid + 256] = src[e1];
        dseg[tid] = dS[pb + tid];
        dseg[tid + 256] = dS[pb + 256 + tid];
    }
    __syncthreads();

    const int lane = tid & 63;
    const int wv   = tid >> 6;
    const int lg   = lane >> 4;   // lane group 0..3
    const int lc   = lane & 15;

    // B fragments (once per kernel): frag(kt,nt) lane holds
    // B[k=kt*32+lg*8+j][col=nt*16+lc] = WbT[(nt*16+lc)*64 + kt*32+lg*8 + j]
    bf16x8 bfr[2][NT];
    #pragma unroll
    for (int kt = 0; kt < 2; kt++)
        #pragma unroll
        for (int nt = 0; nt < NT; nt++)
            bfr[kt][nt] = *reinterpret_cast<const bf16x8*>(
                WbT + (nt * 16 + lc) * 64 + kt * 32 + lg * 8);

    float* msgW = msg[wv];

    #pragma unroll 1
    for (int ch = 0; ch < 4; ++ch) {
        const int rb0 = wv * 128 + ch * 32;
        #pragma unroll
        for (int mt = 0; mt < 2; ++mt) {
            const int rowbase = rb0 + mt * 16;
            // A frags: lane row = lc, k-halves lg*8 within each 32-k tile
            const unsigned* arow = ebf + (unsigned long long)(pb + rowbase + lc) * 32;
            bf16x8 a0 = *reinterpret_cast<const bf16x8*>(arow + lg * 4);
            bf16x8 a1 = *reinterpret_cast<const bf16x8*>(arow + 16 + lg * 4);
            int sr[4];
            #pragma unroll
            for (int r = 0; r < 4; r++) sr[r] = sIdxL[rowbase + lg * 4 + r];
            #pragma unroll
            for (int nt = 0; nt < NT; nt++) {
                f32x4 acc = {0.f, 0.f, 0.f, 0.f};
                acc = __builtin_amdgcn_mfma_f32_16x16x32_bf16(a0, bfr[0][nt], acc, 0, 0, 0);
                acc = __builtin_amdgcn_mfma_f32_16x16x32_bf16(a1, bfr[1][nt], acc, 0, 0, 0);
                const int col = nt * 16 + lc;
                #pragma unroll
                for (int r = 0; r < 4; r++) {
                    float gv = (col < FOUT) ? g[(long long)sr[r] * FOUTP + col] : 0.f;
                    float v  = fmaxf(acc[r] + gv, 0.f);
                    msgW[(mt * 16 + lg * 4 + r) * MS + col] = v;
                }
            }
        }
        // segmented reduce over this chunk's 32 rows (same-wave LDS: no barrier)
        const int base = rb0;
        for (int r0 = 0; r0 < 32; ++r0) {
            int dr = dseg[base + r0];
            if (r0 > 0 && dseg[base + r0 - 1] == dr) continue;  // not seg start
            float s = 0.f;
            int rr = r0;
            while (true) {
                if (lane < NT * 16) s += msgW[rr * MS + lane];
                ++rr;
                if (rr >= 32 || dseg[base + rr] != dr) break;
            }
            if (lane < FOUT) atomicAdd(agg + (long long)dr * FOUT + lane, s);
        }
    }
}

// ===========================================================================
// FALLBACK edge kernel (ws too small for ebf): round-8/10 proven structure.
// ===========================================================================
template<int FOUT, int FOUTP, int MS>
__global__ __launch_bounds__(256) void edge_fb(
    const float* __restrict__ g,
    const float* __restrict__ efeats,
    const int* __restrict__ src,
    const int* __restrict__ eidS,
    const int* __restrict__ dS,
    const float* __restrict__ Wp,
    float* __restrict__ agg)
{
    constexpr int F4 = FOUTP / 4;
    constexpr int ST = 17;
    static_assert(128 * MS + 64 <= 512 * ST, "msg buf exceeds sbuf");

    __shared__ float sbuf[512 * ST];
    __shared__ int   dseg[512];

    const int tid = threadIdx.x;
    const long long pb = (long long)blockIdx.x * 512;
    dseg[tid]       = dS[pb + tid];
    dseg[tid + 256] = dS[pb + 256 + tid];

    const int eid0 = eidS[pb + tid], eid1 = eidS[pb + 256 + tid];
    const int s0 = src[eid0], s1 = src[eid1];
    const float4* gr0 = reinterpret_cast<const float4*>(g + (long long)s0 * FOUTP);
    const float4* gr1 = reinterpret_cast<const float4*>(g + (long long)s1 * FOUTP);
    const float*  er0 = efeats + (long long)eid0 * 64;
    const float*  er1 = efeats + (long long)eid1 * 64;
    const float4* Wp4 = reinterpret_cast<const float4*>(Wp);

    float4 acc0[F4], acc1[F4];
    #pragma unroll
    for (int j4 = 0; j4 < F4; j4++) acc0[j4] = gr0[j4];
    #pragma unroll
    for (int j4 = 0; j4 < F4; j4++) acc1[j4] = gr1[j4];

    const int t0 = tid * ST;
    const int t1 = (tid + 256) * ST;

    for (int c = 0; c < 4; ++c) {
        const int off = c * 16;
        #pragma unroll
        for (int f = 0; f < 4; ++f) {
            float4 v0 = *reinterpret_cast<const float4*>(er0 + off + 4 * f);
            float4 v1 = *reinterpret_cast<const float4*>(er1 + off + 4 * f);
            float* d0 = &sbuf[t0 + 4 * f];
            float* d1 = &sbuf[t1 + 4 * f];
            d0[0] = v0.x; d0[1] = v0.y; d0[2] = v0.z; d0[3] = v0.w;
            d1[0] = v1.x; d1[1] = v1.y; d1[2] = v1.z; d1[3] = v1.w;
        }
        #pragma unroll 1
        for (int k = 0; k < 16; ++k) {
            const float x0 = sbuf[t0 + k];
            const float x1 = sbuf[t1 + k];
            const float4* wrow = &Wp4[(off + k) * F4];
            #pragma unroll
            for (int j4 = 0; j4 < F4; j4++) {
                float4 w = wrow[j4];
                fma4(acc0[j4], w, x0);
                fma4(acc1[j4], w, x1);
            }
        }
    }

    const int lane = tid & 63;
    const int wv   = tid >> 6;

    #pragma unroll 1
    for (int bb = 0; bb < 4; ++bb) {
        __syncthreads();
        if ((tid >> 7) == (bb & 1)) {
            const int r = tid & 127;
            float* mrow = &sbuf[r * MS];
            if (bb < 2) {
                #pragma unroll
                for (int j4 = 0; j4 < F4; j4++) {
                    if (4 * j4 + 0 < FOUT) mrow[4 * j4 + 0] = fmaxf(acc0[j4].x, 0.f);
                    if (4 * j4 + 1 < FOUT) mrow[4 * j4 + 1] = fmaxf(acc0[j4].y, 0.f);
                    if (4 * j4 + 2 < FOUT) mrow[4 * j4 + 2] = fmaxf(acc0[j4].z, 0.f);
                    if (4 * j4 + 3 < FOUT) mrow[4 * j4 + 3] = fmaxf(acc0[j4].w, 0.f);
                }
            } else {
                #pragma unroll
                for (int j4 = 0; j4 < F4; j4++) {
                    if (4 * j4 + 0 < FOUT) mrow[4 * j4 + 0] = fmaxf(acc1[j4].x, 0.f);
                    if (4 * j4 + 1 < FOUT) mrow[4 * j4 + 1] = fmaxf(acc1[j4].y, 0.f);
                    if (4 * j4 + 2 < FOUT) mrow[4 * j4 + 2] = fmaxf(acc1[j4].z, 0.f);
                    if (4 * j4 + 3 < FOUT) mrow[4 * j4 + 3] = fmaxf(acc1[j4].w, 0.f);
                }
            }
        }
        __syncthreads();

        const int rbase = bb * 128;
        for (int r0 = wv * 32; r0 < wv * 32 + 32; ++r0) {
            int dr = dseg[rbase + r0];
            if (r0 > 0 && dseg[rbase + r0 - 1] == dr) continue;
            float s = 0.f;
            int rr = r0;
            while (true) {
                s += sbuf[rr * MS + lane];
                ++rr;
                if (rr >= 128 || dseg[rbase + rr] != dr) break;
            }
            if (lane < FOUT) atomicAdd(agg + (long long)dr * FOUT + lane, s);
        }
    }
}

// ===========================================================================
// Node kernel (fused): h_next = relu(cat(h, agg) @ Wa + ba), plus fused
// g_next = h_next @ Wm_next(h-part) + bm_next when GOUT > 0.
// ===========================================================================
template<int FH, int FHP, int FAGG, int FOUT, int FOUTP, int GOUT, int GOUTP>
__global__ __launch_bounds__(256) void node_kernel(
    const float* __restrict__ h,
    const float* __restrict__ agg,
    const float* __restrict__ Wa,
    const float* __restrict__ ba,
    const float* __restrict__ Wmn,
    const float* __restrict__ bmn,
    float* __restrict__ out,
    float* __restrict__ gout,
    int nNodes)
{
    constexpr int K  = FH + FAGG;
    constexpr int F4 = FOUTP / 4;
    constexpr int G4 = (GOUT > 0) ? GOUTP / 4 : 1;

    __shared__ float4 Wl[K * F4];
    __shared__ float4 Wg[(GOUT > 0) ? FOUTP * G4 : 1];
    __shared__ float  bl[FOUTP];
    __shared__ float  bg[(GOUT > 0) ? GOUTP : 4];

    const int tid = threadIdx.x;
    for (int idx = tid; idx < K * FOUTP; idx += 256) {
        int k = idx / FOUTP, j = idx - k * FOUTP;
        reinterpret_cast<float*>(Wl)[idx] = (j < FOUT) ? Wa[k * FOUT + j] : 0.f;
    }
    for (int idx = tid; idx < FOUTP; idx += 256)
        bl[idx] = (idx < FOUT) ? ba[idx] : 0.f;
    if constexpr (GOUT > 0) {
        for (int idx = tid; idx < FOUTP * GOUTP; idx += 256) {
            int k = idx / GOUTP, j = idx - k * GOUTP;
            reinterpret_cast<float*>(Wg)[idx] =
                (k < FOUT && j < GOUT) ? Wmn[k * GOUT + j] : 0.f;
        }
        for (int idx = tid; idx < GOUTP; idx += 256)
            bg[idx] = (idx < GOUT) ? bmn[idx] : 0.f;
    }
    __syncthreads();

    const int n = blockIdx.x * 256 + tid;
    if (n >= nNodes) return;

    float4 acc[F4];
    #pragma unroll
    for (int j4 = 0; j4 < F4; j4++) acc[j4] = reinterpret_cast<float4*>(bl)[j4];

    const float* hrow = h + (long long)n * FHP;
    #pragma unroll 1
    for (int k = 0; k < FH; k++) {
        float xk = hrow[k];
        const float4* wrow = &Wl[k * F4];
        #pragma unroll
        for (int j4 = 0; j4 < F4; j4++) fma4(acc[j4], wrow[j4], xk);
    }
    const float* arow = agg + (long long)n * FAGG;
    #pragma unroll 1
    for (int k = 0; k < FAGG; k++) {
        float xk = arow[k];
        const float4* wrow = &Wl[(FH + k) * F4];
        #pragma unroll
        for (int j4 = 0; j4 < F4; j4++) fma4(acc[j4], wrow[j4], xk);
    }

    #pragma unroll
    for (int j4 = 0; j4 < F4; j4++) {
        acc[j4].x = fmaxf(acc[j4].x, 0.f);
        acc[j4].y = fmaxf(acc[j4].y, 0.f);
        acc[j4].z = fmaxf(acc[j4].z, 0.f);
        acc[j4].w = fmaxf(acc[j4].w, 0.f);
    }
    float4* orow = reinterpret_cast<float4*>(out + (long long)n * FOUTP);
    #pragma unroll
    for (int j4 = 0; j4 < F4; j4++) orow[j4] = acc[j4];

    if constexpr (GOUT > 0) {
        float4 gacc[G4];
        #pragma unroll
        for (int j4 = 0; j4 < G4; j4++) gacc[j4] = reinterpret_cast<float4*>(bg)[j4];
        #pragma unroll 1
        for (int k4 = 0; k4 < F4; ++k4) {
            float4 xv = acc[k4];
            #pragma unroll
            for (int c = 0; c < 4; ++c) {
                float xc = (c == 0) ? xv.x : (c == 1) ? xv.y : (c == 2) ? xv.z : xv.w;
                const float4* wrow = &Wg[(k4 * 4 + c) * G4];
                #pragma unroll
                for (int j4 = 0; j4 < G4; j4++) fma4(gacc[j4], wrow[j4], xc);
            }
        }
        float4* grow = reinterpret_cast<float4*>(gout + (long long)n * GOUTP);
        #pragma unroll
        for (int j4 = 0; j4 < G4; j4++) grow[j4] = gacc[j4];
    }
}

extern "C" void kernel_launch(void* const* d_in, const int* in_sizes, int n_in,
                              void* d_out, int out_size, void* d_ws, size_t ws_size,
                              hipStream_t stream)
{
    const float* nfeats = (const float*)d_in[0];
    const float* efeats = (const float*)d_in[1];
    const int*   src    = (const int*)d_in[2];
    const int*   dst    = (const int*)d_in[3];
    const float* Wm1 = (const float*)d_in[4],  *bm1 = (const float*)d_in[5];
    const float* Wa1 = (const float*)d_in[6],  *ba1 = (const float*)d_in[7];
    const float* Wm2 = (const float*)d_in[8],  *bm2 = (const float*)d_in[9];
    const float* Wa2 = (const float*)d_in[10], *ba2 = (const float*)d_in[11];
    const float* Wm3 = (const float*)d_in[12], *bm3 = (const float*)d_in[13];
    const float* Wa3 = (const float*)d_in[14], *ba3 = (const float*)d_in[15];
    float* out = (float*)d_out;

    constexpr int N = 100000;
    constexpr int E = 3200000;                      // % 512 == 0
    constexpr int SCAN_BLOCKS = (N + 1023) / 1024;  // 98

    // ---- base layout: round-8/10 proven footprint + small bf16 W tables ----
    float* ws   = (float*)d_ws;
    float* h1   = ws;                            // N x 52
    float* h2   = h1 + (size_t)N * 52;           // N x 28
    float* agg  = h2 + (size_t)N * 28;           // N x 52
    float* g    = agg + (size_t)N * 52;          // N x 52
    int* counts = (int*)(g + (size_t)N * 52);    // N
    int* cursor = counts + N;                    // N
    int* bsums  = cursor + N;                    // 128
    int* eidS   = bsums + 128;                   // E
    int* dS     = eidS + E;                      // E
    float* Wp1  = (float*)(dS + E);              // 64 x 52 fp32 (fallback)
    float* Wp2  = Wp1 + 64 * 52;                 // 64 x 28
    float* Wp3  = Wp2 + 64 * 28;                 // 64 x 32
    unsigned short* Wb1 = (unsigned short*)(Wp3 + 64 * 32); // 64 x 64 bf16
    unsigned short* Wb2 = Wb1 + 64 * 64;                    // 32 x 64 bf16
    unsigned short* Wb3 = Wb2 + 32 * 64;                    // 32 x 64 bf16
    char* endp = (char*)(Wb3 + 32 * 64);

    size_t usedB   = (size_t)(endp - (char*)d_ws);
    size_t ebfOffB = (usedB + 127) & ~(size_t)127;
    size_t neededB = ebfOffB + (size_t)E * 128;  // + E x 32 u32 bf16 rows
    const bool useBf = (ws_size >= neededB);
    unsigned* ebf = (unsigned*)((char*)d_ws + ebfOffB);

    // ---- pack W tables ----
    pack_we<64, 50, 52><<<(64 * 52 + 255) / 256, 256, 0, stream>>>(Wm1, Wp1);
    pack_we<50, 25, 28><<<(64 * 28 + 255) / 256, 256, 0, stream>>>(Wm2, Wp2);
    pack_we<25, 32, 32><<<(64 * 32 + 255) / 256, 256, 0, stream>>>(Wm3, Wp3);
    pack_wbt<64, 50, 64><<<(64 * 64 + 255) / 256, 256, 0, stream>>>(Wm1, Wb1);
    pack_wbt<50, 25, 32><<<(32 * 64 + 255) / 256, 256, 0, stream>>>(Wm2, Wb2);
    pack_wbt<25, 32, 32><<<(32 * 64 + 255) / 256, 256, 0, stream>>>(Wm3, Wb3);

    // ---- CSR build (counting sort by dst) ----
    hipMemsetAsync(counts, 0, (size_t)N * sizeof(int), stream);
    hist_kernel<<<2048, 256, 0, stream>>>(dst, counts, E);
    scan_block<<<SCAN_BLOCKS, 1024, 0, stream>>>(counts, cursor, bsums, N);
    scan_small<<<1, 64, 0, stream>>>(bsums, SCAN_BLOCKS);
    add_offsets<<<SCAN_BLOCKS, 1024, 0, stream>>>(cursor, bsums, N);
    scatter_kernel<<<2048, 256, 0, stream>>>(dst, cursor, eidS, dS, E);

    // ---- one-time gather + bf16 convert of efeats into sorted order ----
    if (useBf)
        permute_convert<<<E / 256, 256, 0, stream>>>(efeats, eidS, ebf);

    const int EB = E / 512;
    const int NB = (N + 255) / 256;

    // ---- g1 = nfeats @ Wm1(h-part) + bm1 ----
    gemv_g<64, 50, 52><<<NB, 256, 0, stream>>>(nfeats, Wm1, bm1, g, N);

    // ---- layer 1 ----
    hipMemsetAsync(agg, 0, (size_t)N * 52 * sizeof(float), stream);
    if (useBf)
        edge_mfma<50, 52, 4><<<EB, 256, 0, stream>>>(g, ebf, src, eidS, dS, Wb1, agg);
    else
        edge_fb<50, 52, 51><<<EB, 256, 0, stream>>>(g, efeats, src, eidS, dS, Wp1, agg);
    node_kernel<64, 64, 50, 50, 52, 25, 28><<<NB, 256, 0, stream>>>(
        nfeats, agg, Wa1, ba1, Wm2, bm2, h1, g, N);

    // ---- layer 2 ----
    hipMemsetAsync(agg, 0, (size_t)N * 52 * sizeof(float), stream);
    if (useBf)
        edge_mfma<25, 28, 2><<<EB, 256, 0, stream>>>(g, ebf, src, eidS, dS, Wb2, agg);
    else
        edge_fb<25, 28, 25><<<EB, 256, 0, stream>>>(g, efeats, src, eidS, dS, Wp2, agg);
    node_kernel<50, 52, 25, 25, 28, 32, 32><<<NB, 256, 0, stream>>>(
        h1, agg, Wa2, ba2, Wm3, bm3, h2, g, N);

    // ---- layer 3 ----
    hipMemsetAsync(agg, 0, (size_t)N * 52 * sizeof(float), stream);
    if (useBf)
        edge_mfma<32, 32, 2><<<EB, 256, 0, stream>>>(g, ebf, src, eidS, dS, Wb3, agg);
    else
        edge_fb<32, 32, 33><<<EB, 256, 0, stream>>>(g, efeats, src, eidS, dS, Wp3, agg);
    node_kernel<25, 28, 32, 32, 32, 0, 0><<<NB, 256, 0, stream>>>(
        h2, agg, Wa3, ba3, nullptr, nullptr, out, nullptr, N);
}

// Round 12
// 1441.043 us; speedup vs baseline: 19.9713x; 1.2327x over previous
//
#include <hip/hip_runtime.h>

#define DEVINL __device__ __forceinline__

typedef __attribute__((ext_vector_type(8))) short bf16x8;
typedef __attribute__((ext_vector_type(4))) float f32x4;

DEVINL void fma4(float4& a, const float4 w, const float x) {
    a.x += w.x * x; a.y += w.y * x; a.z += w.z * x; a.w += w.w * x;
}

DEVINL unsigned short bf16of(float x) {
    unsigned a = __float_as_uint(x);
    a += 0x7FFFu + ((a >> 16) & 1u);
    return (unsigned short)(a >> 16);
}

// pack two fp32 into one u32 of 2 bf16 (RNE); element "lo" in low half
DEVINL unsigned bfpair(float lo, float hi) {
    unsigned a = __float_as_uint(lo);
    a += 0x7FFFu + ((a >> 16) & 1u);
    unsigned b = __float_as_uint(hi);
    b += 0x7FFFu + ((b >> 16) & 1u);
    return (a >> 16) | (b & 0xFFFF0000u);
}

DEVINL bf16x8 as_bf16x8(uint4 u) {
    union { uint4 u4; bf16x8 b; } cv; cv.u4 = u; return cv.b;
}

// ===========================================================================
// CSR build: counting sort of edges by dst. Payload packed as int4
// {eid, dst, src, 0} -> ONE scattered 16B line per edge (was 2-3).
// ===========================================================================
__global__ __launch_bounds__(256) void hist_kernel(const int* __restrict__ d,
                                                   int* __restrict__ counts, int n) {
    for (int i = blockIdx.x * 256 + threadIdx.x; i < n; i += gridDim.x * 256)
        atomicAdd(&counts[d[i]], 1);
}

__global__ __launch_bounds__(1024) void scan_block(const int* __restrict__ in,
                                                   int* __restrict__ out,
                                                   int* __restrict__ bsums, int n) {
    __shared__ int buf[2][1024];
    const int t = threadIdx.x;
    const int i = blockIdx.x * 1024 + t;
    const int v = (i < n) ? in[i] : 0;
    int cur = 0;
    buf[0][t] = v;
    __syncthreads();
    #pragma unroll
    for (int s = 1; s < 1024; s <<= 1) {
        int x = buf[cur][t];
        if (t >= s) x += buf[cur][t - s];
        buf[cur ^ 1][t] = x;
        cur ^= 1;
        __syncthreads();
    }
    if (i < n) out[i] = buf[cur][t] - v;            // exclusive
    if (t == 1023) bsums[blockIdx.x] = buf[cur][t]; // block total
}

__global__ void scan_small(int* __restrict__ bs, int nb) {
    if (blockIdx.x == 0 && threadIdx.x == 0) {
        int acc = 0;
        for (int i = 0; i < nb; i++) { int v = bs[i]; bs[i] = acc; acc += v; }
    }
}

__global__ __launch_bounds__(1024) void add_offsets(int* __restrict__ out,
                                                    const int* __restrict__ bs, int n) {
    int i = blockIdx.x * 1024 + threadIdx.x;
    if (i < n) out[i] += bs[blockIdx.x];
}

__global__ __launch_bounds__(256) void scatter_kernel(const int* __restrict__ d,
                                                      const int* __restrict__ src,
                                                      int* __restrict__ cursor,
                                                      int4* __restrict__ recs, int n) {
    for (int i = blockIdx.x * 256 + threadIdx.x; i < n; i += gridDim.x * 256) {
        int dd = d[i];
        int ss = src[i];
        int pos = atomicAdd(&cursor[dd], 1);
        recs[pos] = make_int4(i, dd, ss, 0);
    }
}

// ===========================================================================
// pack_we (fp32, fallback path): e-part rows -> padded [64][FOUTP].
// ===========================================================================
template<int FIN, int FOUT, int FOUTP>
__global__ __launch_bounds__(256) void pack_we(const float* __restrict__ W,
                                               float* __restrict__ Wp) {
    int idx = blockIdx.x * 256 + threadIdx.x;
    if (idx >= 64 * FOUTP) return;
    int k = idx / FOUTP, j = idx - k * FOUTP;
    Wp[idx] = (j < FOUT) ? W[(FIN + k) * FOUT + j] : 0.f;
}

// ===========================================================================
// pack_wbt: e-part of Wm -> bf16 TRANSPOSED table WbT[col][64], col padded
// to NC with zeros. Row stride 64 bf16 = 128B (16B-aligned frag loads).
// ===========================================================================
template<int FIN, int FOUT, int NC>
__global__ __launch_bounds__(256) void pack_wbt(const float* __restrict__ W,
                                                unsigned short* __restrict__ WbT) {
    int idx = blockIdx.x * 256 + threadIdx.x;
    if (idx >= NC * 64) return;
    int c = idx / 64, k = idx - c * 64;
    WbT[idx] = (c < FOUT) ? bf16of(W[(FIN + k) * FOUT + c]) : (unsigned short)0;
}

// ===========================================================================
// gemv_g: g = x @ W(h-part rows [0,FIN)) + b, padded to FOUTP.
// ===========================================================================
template<int FIN, int FOUT, int FOUTP>
__global__ __launch_bounds__(256) void gemv_g(
    const float* __restrict__ x,
    const float* __restrict__ W,
    const float* __restrict__ b,
    float* __restrict__ g, int nNodes)
{
    constexpr int F4 = FOUTP / 4;
    __shared__ float4 Wl[FIN * F4];
    __shared__ float  bl[FOUTP];
    const int tid = threadIdx.x;
    for (int idx = tid; idx < FIN * FOUTP; idx += 256) {
        int k = idx / FOUTP, j = idx - k * FOUTP;
        reinterpret_cast<float*>(Wl)[idx] = (j < FOUT) ? W[k * FOUT + j] : 0.f;
    }
    for (int idx = tid; idx < FOUTP; idx += 256)
        bl[idx] = (idx < FOUT) ? b[idx] : 0.f;
    __syncthreads();
    const int n = blockIdx.x * 256 + tid;
    if (n >= nNodes) return;
    float4 acc[F4];
    #pragma unroll
    for (int j4 = 0; j4 < F4; j4++) acc[j4] = reinterpret_cast<float4*>(bl)[j4];
    const float* xr = x + (long long)n * FIN;
    #pragma unroll 1
    for (int k = 0; k < FIN; ++k) {
        float xk = xr[k];
        const float4* wrow = &Wl[k * F4];
        #pragma unroll
        for (int j4 = 0; j4 < F4; j4++) fma4(acc[j4], wrow[j4], xk);
    }
    float4* gr = reinterpret_cast<float4*>(g + (long long)n * FOUTP);
    #pragma unroll
    for (int j4 = 0; j4 < F4; j4++) gr[j4] = acc[j4];
}

// ===========================================================================
// Shared epilogue helpers are inlined in each kernel (wave-private msg tile,
// segmented reduce by sorted dst; NO barriers in the main loop).
// MFMA frag semantics (HW-verified in round 11, absmax-checked):
//   A lane: row = l&15, k = (l>>4)*8 + j   (bf16x8)
//   B lane: col = l&15, k = (l>>4)*8 + j
//   D lane: col = l&15, row = (l>>4)*4 + reg
// ===========================================================================

// ---------------------------------------------------------------------------
// Layer-1 edge kernel WITH fused gather+convert: reads fp32 efeats rows by
// eid (random 256B rows, each line fetched once by 4 lanes), converts to
// bf16 in-register, WRITES the sorted bf16 stream (for layers 2/3), and
// feeds its own MFMA. Deletes the separate permute_convert pass.
// ---------------------------------------------------------------------------
template<int FOUT, int FOUTP, int NT>
__global__ __launch_bounds__(256) void edge_mfma_cvt(
    const float* __restrict__ g,
    const float* __restrict__ efeats,
    const int4* __restrict__ recs,    // sorted {eid, dst, src, 0}
    const unsigned short* __restrict__ WbT,
    unsigned* __restrict__ ebf,       // out: [E][32] u32 bf16-pairs, sorted
    float* __restrict__ agg)
{
    constexpr int MS = NT * 16 + 1;

    __shared__ float msg[4][32 * MS];
    __shared__ int eidL[512], sIdxL[512], dseg[512];

    const int tid = threadIdx.x;
    const long long pb = (long long)blockIdx.x * 512;
    {
        int4 r0 = recs[pb + tid];
        int4 r1 = recs[pb + 256 + tid];
        eidL[tid] = r0.x;  dseg[tid] = r0.y;  sIdxL[tid] = r0.z;
        eidL[tid + 256] = r1.x; dseg[tid + 256] = r1.y; sIdxL[tid + 256] = r1.z;
    }
    __syncthreads();

    const int lane = tid & 63;
    const int wv   = tid >> 6;
    const int lg   = lane >> 4;
    const int lc   = lane & 15;

    bf16x8 bfr[2][NT];
    #pragma unroll
    for (int kt = 0; kt < 2; kt++)
        #pragma unroll
        for (int nt = 0; nt < NT; nt++)
            bfr[kt][nt] = *reinterpret_cast<const bf16x8*>(
                WbT + (nt * 16 + lc) * 64 + kt * 32 + lg * 8);

    float* msgW = msg[wv];

    #pragma unroll 1
    for (int ch = 0; ch < 4; ++ch) {
        const int rb0 = wv * 128 + ch * 32;
        #pragma unroll
        for (int mt = 0; mt < 2; ++mt) {
            const int rowbase = rb0 + mt * 16;
            // gather fp32 row (4 lanes x 64B cover the 256B row once)
            const int eid = eidL[rowbase + lc];
            const float4* erow = reinterpret_cast<const float4*>(efeats + (long long)eid * 64);
            float4 f0 = erow[lg * 2];
            float4 f1 = erow[lg * 2 + 1];
            float4 f2 = erow[8 + lg * 2];
            float4 f3 = erow[8 + lg * 2 + 1];
            uint4 u0, u1;
            u0.x = bfpair(f0.x, f0.y); u0.y = bfpair(f0.z, f0.w);
            u0.z = bfpair(f1.x, f1.y); u0.w = bfpair(f1.z, f1.w);
            u1.x = bfpair(f2.x, f2.y); u1.y = bfpair(f2.z, f2.w);
            u1.z = bfpair(f3.x, f3.y); u1.w = bfpair(f3.z, f3.w);
            // emit sorted bf16 stream for layers 2/3
            uint4* eb = reinterpret_cast<uint4*>(ebf + (unsigned long long)(pb + rowbase + lc) * 32);
            eb[lg]     = u0;
            eb[4 + lg] = u1;
            bf16x8 a0 = as_bf16x8(u0);
            bf16x8 a1 = as_bf16x8(u1);

            int sr[4];
            #pragma unroll
            for (int r = 0; r < 4; r++) sr[r] = sIdxL[rowbase + lg * 4 + r];
            #pragma unroll
            for (int nt = 0; nt < NT; nt++) {
                f32x4 acc = {0.f, 0.f, 0.f, 0.f};
                acc = __builtin_amdgcn_mfma_f32_16x16x32_bf16(a0, bfr[0][nt], acc, 0, 0, 0);
                acc = __builtin_amdgcn_mfma_f32_16x16x32_bf16(a1, bfr[1][nt], acc, 0, 0, 0);
                const int col = nt * 16 + lc;
                #pragma unroll
                for (int r = 0; r < 4; r++) {
                    float gv = (col < FOUT) ? g[(long long)sr[r] * FOUTP + col] : 0.f;
                    float v  = fmaxf(acc[r] + gv, 0.f);
                    msgW[(mt * 16 + lg * 4 + r) * MS + col] = v;
                }
            }
        }
        const int base = rb0;
        for (int r0 = 0; r0 < 32; ++r0) {
            int dr = dseg[base + r0];
            if (r0 > 0 && dseg[base + r0 - 1] == dr) continue;
            float s = 0.f;
            int rr = r0;
            while (true) {
                s += msgW[rr * MS + lane];
                ++rr;
                if (rr >= 32 || dseg[base + rr] != dr) break;
            }
            if (lane < FOUT) atomicAdd(agg + (long long)dr * FOUT + lane, s);
        }
    }
}

// ---------------------------------------------------------------------------
// Layers 2/3 edge kernel: A-frags straight from the sequential bf16 stream.
// ---------------------------------------------------------------------------
template<int FOUT, int FOUTP, int NT>
__global__ __launch_bounds__(256) void edge_mfma(
    const float* __restrict__ g,
    const unsigned* __restrict__ ebf,
    const int4* __restrict__ recs,
    const unsigned short* __restrict__ WbT,
    float* __restrict__ agg)
{
    constexpr int MS = NT * 16 + 1;

    __shared__ float msg[4][32 * MS];
    __shared__ int sIdxL[512], dseg[512];

    const int tid = threadIdx.x;
    const long long pb = (long long)blockIdx.x * 512;
    {
        int4 r0 = recs[pb + tid];
        int4 r1 = recs[pb + 256 + tid];
        dseg[tid] = r0.y;  sIdxL[tid] = r0.z;
        dseg[tid + 256] = r1.y; sIdxL[tid + 256] = r1.z;
    }
    __syncthreads();

    const int lane = tid & 63;
    const int wv   = tid >> 6;
    const int lg   = lane >> 4;
    const int lc   = lane & 15;

    bf16x8 bfr[2][NT];
    #pragma unroll
    for (int kt = 0; kt < 2; kt++)
        #pragma unroll
        for (int nt = 0; nt < NT; nt++)
            bfr[kt][nt] = *reinterpret_cast<const bf16x8*>(
                WbT + (nt * 16 + lc) * 64 + kt * 32 + lg * 8);

    float* msgW = msg[wv];

    #pragma unroll 1
    for (int ch = 0; ch < 4; ++ch) {
        const int rb0 = wv * 128 + ch * 32;
        #pragma unroll
        for (int mt = 0; mt < 2; ++mt) {
            const int rowbase = rb0 + mt * 16;
            const unsigned* arow = ebf + (unsigned long long)(pb + rowbase + lc) * 32;
            bf16x8 a0 = *reinterpret_cast<const bf16x8*>(arow + lg * 4);
            bf16x8 a1 = *reinterpret_cast<const bf16x8*>(arow + 16 + lg * 4);
            int sr[4];
            #pragma unroll
            for (int r = 0; r < 4; r++) sr[r] = sIdxL[rowbase + lg * 4 + r];
            #pragma unroll
            for (int nt = 0; nt < NT; nt++) {
                f32x4 acc = {0.f, 0.f, 0.f, 0.f};
                acc = __builtin_amdgcn_mfma_f32_16x16x32_bf16(a0, bfr[0][nt], acc, 0, 0, 0);
                acc = __builtin_amdgcn_mfma_f32_16x16x32_bf16(a1, bfr[1][nt], acc, 0, 0, 0);
                const int col = nt * 16 + lc;
                #pragma unroll
                for (int r = 0; r < 4; r++) {
                    float gv = (col < FOUT) ? g[(long long)sr[r] * FOUTP + col] : 0.f;
                    float v  = fmaxf(acc[r] + gv, 0.f);
                    msgW[(mt * 16 + lg * 4 + r) * MS + col] = v;
                }
            }
        }
        const int base = rb0;
        for (int r0 = 0; r0 < 32; ++r0) {
            int dr = dseg[base + r0];
            if (r0 > 0 && dseg[base + r0 - 1] == dr) continue;
            float s = 0.f;
            int rr = r0;
            while (true) {
                s += msgW[rr * MS + lane];
                ++rr;
                if (rr >= 32 || dseg[base + rr] != dr) break;
            }
            if (lane < FOUT) atomicAdd(agg + (long long)dr * FOUT + lane, s);
        }
    }
}

// ===========================================================================
// FALLBACK edge kernel (ws too small for ebf): round-10 proven structure,
// fp32 efeats gather, reads recs.
// ===========================================================================
template<int FOUT, int FOUTP, int MS>
__global__ __launch_bounds__(256) void edge_fb(
    const float* __restrict__ g,
    const float* __restrict__ efeats,
    const int4* __restrict__ recs,
    const float* __restrict__ Wp,
    float* __restrict__ agg)
{
    constexpr int F4 = FOUTP / 4;
    constexpr int ST = 17;
    static_assert(128 * MS + 64 <= 512 * ST, "msg buf exceeds sbuf");

    __shared__ float sbuf[512 * ST];
    __shared__ int   dseg[512];

    const int tid = threadIdx.x;
    const long long pb = (long long)blockIdx.x * 512;
    int4 r0 = recs[pb + tid];
    int4 r1 = recs[pb + 256 + tid];
    dseg[tid] = r0.y;
    dseg[tid + 256] = r1.y;

    const float4* gr0 = reinterpret_cast<const float4*>(g + (long long)r0.z * FOUTP);
    const float4* gr1 = reinterpret_cast<const float4*>(g + (long long)r1.z * FOUTP);
    const float*  er0 = efeats + (long long)r0.x * 64;
    const float*  er1 = efeats + (long long)r1.x * 64;
    const float4* Wp4 = reinterpret_cast<const float4*>(Wp);

    float4 acc0[F4], acc1[F4];
    #pragma unroll
    for (int j4 = 0; j4 < F4; j4++) acc0[j4] = gr0[j4];
    #pragma unroll
    for (int j4 = 0; j4 < F4; j4++) acc1[j4] = gr1[j4];

    const int t0 = tid * ST;
    const int t1 = (tid + 256) * ST;

    for (int c = 0; c < 4; ++c) {
        const int off = c * 16;
        #pragma unroll
        for (int f = 0; f < 4; ++f) {
            float4 v0 = *reinterpret_cast<const float4*>(er0 + off + 4 * f);
            float4 v1 = *reinterpret_cast<const float4*>(er1 + off + 4 * f);
            float* d0 = &sbuf[t0 + 4 * f];
            float* d1 = &sbuf[t1 + 4 * f];
            d0[0] = v0.x; d0[1] = v0.y; d0[2] = v0.z; d0[3] = v0.w;
            d1[0] = v1.x; d1[1] = v1.y; d1[2] = v1.z; d1[3] = v1.w;
        }
        #pragma unroll 1
        for (int k = 0; k < 16; ++k) {
            const float x0 = sbuf[t0 + k];
            const float x1 = sbuf[t1 + k];
            const float4* wrow = &Wp4[(off + k) * F4];
            #pragma unroll
            for (int j4 = 0; j4 < F4; j4++) {
                float4 w = wrow[j4];
                fma4(acc0[j4], w, x0);
                fma4(acc1[j4], w, x1);
            }
        }
    }

    const int lane = tid & 63;
    const int wv   = tid >> 6;

    #pragma unroll 1
    for (int bb = 0; bb < 4; ++bb) {
        __syncthreads();
        if ((tid >> 7) == (bb & 1)) {
            const int r = tid & 127;
            float* mrow = &sbuf[r * MS];
            const float4* accp = (bb < 2) ? acc0 : acc1;
            #pragma unroll
            for (int j4 = 0; j4 < F4; j4++) {
                float4 a = accp[j4];
                if (4 * j4 + 0 < FOUT) mrow[4 * j4 + 0] = fmaxf(a.x, 0.f);
                if (4 * j4 + 1 < FOUT) mrow[4 * j4 + 1] = fmaxf(a.y, 0.f);
                if (4 * j4 + 2 < FOUT) mrow[4 * j4 + 2] = fmaxf(a.z, 0.f);
                if (4 * j4 + 3 < FOUT) mrow[4 * j4 + 3] = fmaxf(a.w, 0.f);
            }
        }
        __syncthreads();

        const int rbase = bb * 128;
        for (int r0i = wv * 32; r0i < wv * 32 + 32; ++r0i) {
            int dr = dseg[rbase + r0i];
            if (r0i > 0 && dseg[rbase + r0i - 1] == dr) continue;
            float s = 0.f;
            int rr = r0i;
            while (true) {
                s += sbuf[rr * MS + lane];
                ++rr;
                if (rr >= 128 || dseg[rbase + rr] != dr) break;
            }
            if (lane < FOUT) atomicAdd(agg + (long long)dr * FOUT + lane, s);
        }
    }
}

// ===========================================================================
// Node kernel (fused): h_next = relu(cat(h, agg) @ Wa + ba), plus fused
// g_next = h_next @ Wm_next(h-part) + bm_next when GOUT > 0.
// ===========================================================================
template<int FH, int FHP, int FAGG, int FOUT, int FOUTP, int GOUT, int GOUTP>
__global__ __launch_bounds__(256) void node_kernel(
    const float* __restrict__ h,
    const float* __restrict__ agg,
    const float* __restrict__ Wa,
    const float* __restrict__ ba,
    const float* __restrict__ Wmn,
    const float* __restrict__ bmn,
    float* __restrict__ out,
    float* __restrict__ gout,
    int nNodes)
{
    constexpr int K  = FH + FAGG;
    constexpr int F4 = FOUTP / 4;
    constexpr int G4 = (GOUT > 0) ? GOUTP / 4 : 1;

    __shared__ float4 Wl[K * F4];
    __shared__ float4 Wg[(GOUT > 0) ? FOUTP * G4 : 1];
    __shared__ float  bl[FOUTP];
    __shared__ float  bg[(GOUT > 0) ? GOUTP : 4];

    const int tid = threadIdx.x;
    for (int idx = tid; idx < K * FOUTP; idx += 256) {
        int k = idx / FOUTP, j = idx - k * FOUTP;
        reinterpret_cast<float*>(Wl)[idx] = (j < FOUT) ? Wa[k * FOUT + j] : 0.f;
    }
    for (int idx = tid; idx < FOUTP; idx += 256)
        bl[idx] = (idx < FOUT) ? ba[idx] : 0.f;
    if constexpr (GOUT > 0) {
        for (int idx = tid; idx < FOUTP * GOUTP; idx += 256) {
            int k = idx / GOUTP, j = idx - k * GOUTP;
            reinterpret_cast<float*>(Wg)[idx] =
                (k < FOUT && j < GOUT) ? Wmn[k * GOUT + j] : 0.f;
        }
        for (int idx = tid; idx < GOUTP; idx += 256)
            bg[idx] = (idx < GOUT) ? bmn[idx] : 0.f;
    }
    __syncthreads();

    const int n = blockIdx.x * 256 + tid;
    if (n >= nNodes) return;

    float4 acc[F4];
    #pragma unroll
    for (int j4 = 0; j4 < F4; j4++) acc[j4] = reinterpret_cast<float4*>(bl)[j4];

    const float* hrow = h + (long long)n * FHP;
    #pragma unroll 1
    for (int k = 0; k < FH; k++) {
        float xk = hrow[k];
        const float4* wrow = &Wl[k * F4];
        #pragma unroll
        for (int j4 = 0; j4 < F4; j4++) fma4(acc[j4], wrow[j4], xk);
    }
    const float* arow = agg + (long long)n * FAGG;
    #pragma unroll 1
    for (int k = 0; k < FAGG; k++) {
        float xk = arow[k];
        const float4* wrow = &Wl[(FH + k) * F4];
        #pragma unroll
        for (int j4 = 0; j4 < F4; j4++) fma4(acc[j4], wrow[j4], xk);
    }

    #pragma unroll
    for (int j4 = 0; j4 < F4; j4++) {
        acc[j4].x = fmaxf(acc[j4].x, 0.f);
        acc[j4].y = fmaxf(acc[j4].y, 0.f);
        acc[j4].z = fmaxf(acc[j4].z, 0.f);
        acc[j4].w = fmaxf(acc[j4].w, 0.f);
    }
    float4* orow = reinterpret_cast<float4*>(out + (long long)n * FOUTP);
    #pragma unroll
    for (int j4 = 0; j4 < F4; j4++) orow[j4] = acc[j4];

    if constexpr (GOUT > 0) {
        float4 gacc[G4];
        #pragma unroll
        for (int j4 = 0; j4 < G4; j4++) gacc[j4] = reinterpret_cast<float4*>(bg)[j4];
        #pragma unroll 1
        for (int k4 = 0; k4 < F4; ++k4) {
            float4 xv = acc[k4];
            #pragma unroll
            for (int c = 0; c < 4; ++c) {
                float xc = (c == 0) ? xv.x : (c == 1) ? xv.y : (c == 2) ? xv.z : xv.w;
                const float4* wrow = &Wg[(k4 * 4 + c) * G4];
                #pragma unroll
                for (int j4 = 0; j4 < G4; j4++) fma4(gacc[j4], wrow[j4], xc);
            }
        }
        float4* grow = reinterpret_cast<float4*>(gout + (long long)n * GOUTP);
        #pragma unroll
        for (int j4 = 0; j4 < G4; j4++) grow[j4] = gacc[j4];
    }
}

extern "C" void kernel_launch(void* const* d_in, const int* in_sizes, int n_in,
                              void* d_out, int out_size, void* d_ws, size_t ws_size,
                              hipStream_t stream)
{
    const float* nfeats = (const float*)d_in[0];
    const float* efeats = (const float*)d_in[1];
    const int*   src    = (const int*)d_in[2];
    const int*   dst    = (const int*)d_in[3];
    const float* Wm1 = (const float*)d_in[4],  *bm1 = (const float*)d_in[5];
    const float* Wa1 = (const float*)d_in[6],  *ba1 = (const float*)d_in[7];
    const float* Wm2 = (const float*)d_in[8],  *bm2 = (const float*)d_in[9];
    const float* Wa2 = (const float*)d_in[10], *ba2 = (const float*)d_in[11];
    const float* Wm3 = (const float*)d_in[12], *bm3 = (const float*)d_in[13];
    const float* Wa3 = (const float*)d_in[14], *ba3 = (const float*)d_in[15];
    float* out = (float*)d_out;

    constexpr int N = 100000;
    constexpr int E = 3200000;                      // % 512 == 0
    constexpr int SCAN_BLOCKS = (N + 1023) / 1024;  // 98

    float* ws   = (float*)d_ws;
    float* h1   = ws;                            // N x 52
    float* h2   = h1 + (size_t)N * 52;           // N x 28
    float* agg  = h2 + (size_t)N * 28;           // N x 52
    float* g    = agg + (size_t)N * 52;          // N x 52
    int* counts = (int*)(g + (size_t)N * 52);    // N
    int* cursor = counts + N;                    // N
    int* bsums  = cursor + N;                    // 128
    int4* recs  = (int4*)(bsums + 128);          // E x 16B (offset 16B-aligned)
    float* Wp1  = (float*)(recs + E);            // 64 x 52 fp32 (fallback)
    float* Wp2  = Wp1 + 64 * 52;                 // 64 x 28
    float* Wp3  = Wp2 + 64 * 28;                 // 64 x 32
    unsigned short* Wb1 = (unsigned short*)(Wp3 + 64 * 32); // 64 x 64 bf16
    unsigned short* Wb2 = Wb1 + 64 * 64;                    // 32 x 64 bf16
    unsigned short* Wb3 = Wb2 + 32 * 64;                    // 32 x 64 bf16
    char* endp = (char*)(Wb3 + 32 * 64);

    size_t usedB   = (size_t)(endp - (char*)d_ws);
    size_t ebfOffB = (usedB + 127) & ~(size_t)127;
    size_t neededB = ebfOffB + (size_t)E * 128;  // + E x 32 u32 bf16 rows
    const bool useBf = (ws_size >= neededB);
    unsigned* ebf = (unsigned*)((char*)d_ws + ebfOffB);

    // ---- pack W tables ----
    pack_we<64, 50, 52><<<(64 * 52 + 255) / 256, 256, 0, stream>>>(Wm1, Wp1);
    pack_we<50, 25, 28><<<(64 * 28 + 255) / 256, 256, 0, stream>>>(Wm2, Wp2);
    pack_we<25, 32, 32><<<(64 * 32 + 255) / 256, 256, 0, stream>>>(Wm3, Wp3);
    pack_wbt<64, 50, 64><<<(64 * 64 + 255) / 256, 256, 0, stream>>>(Wm1, Wb1);
    pack_wbt<50, 25, 32><<<(32 * 64 + 255) / 256, 256, 0, stream>>>(Wm2, Wb2);
    pack_wbt<25, 32, 32><<<(32 * 64 + 255) / 256, 256, 0, stream>>>(Wm3, Wb3);

    // ---- CSR build (counting sort by dst; payload = int4 record) ----
    hipMemsetAsync(counts, 0, (size_t)N * sizeof(int), stream);
    hist_kernel<<<2048, 256, 0, stream>>>(dst, counts, E);
    scan_block<<<SCAN_BLOCKS, 1024, 0, stream>>>(counts, cursor, bsums, N);
    scan_small<<<1, 64, 0, stream>>>(bsums, SCAN_BLOCKS);
    add_offsets<<<SCAN_BLOCKS, 1024, 0, stream>>>(cursor, bsums, N);
    scatter_kernel<<<2048, 256, 0, stream>>>(dst, src, cursor, recs, E);

    const int EB = E / 512;
    const int NB = (N + 255) / 256;

    // ---- g1 = nfeats @ Wm1(h-part) + bm1 ----
    gemv_g<64, 50, 52><<<NB, 256, 0, stream>>>(nfeats, Wm1, bm1, g, N);

    // ---- layer 1 (fused gather+convert -> emits ebf for layers 2/3) ----
    hipMemsetAsync(agg, 0, (size_t)N * 52 * sizeof(float), stream);
    if (useBf)
        edge_mfma_cvt<50, 52, 4><<<EB, 256, 0, stream>>>(g, efeats, recs, Wb1, ebf, agg);
    else
        edge_fb<50, 52, 51><<<EB, 256, 0, stream>>>(g, efeats, recs, Wp1, agg);
    node_kernel<64, 64, 50, 50, 52, 25, 28><<<NB, 256, 0, stream>>>(
        nfeats, agg, Wa1, ba1, Wm2, bm2, h1, g, N);

    // ---- layer 2 ----
    hipMemsetAsync(agg, 0, (size_t)N * 52 * sizeof(float), stream);
    if (useBf)
        edge_mfma<25, 28, 2><<<EB, 256, 0, stream>>>(g, ebf, recs, Wb2, agg);
    else
        edge_fb<25, 28, 25><<<EB, 256, 0, stream>>>(g, efeats, recs, Wp2, agg);
    node_kernel<50, 52, 25, 25, 28, 32, 32><<<NB, 256, 0, stream>>>(
        h1, agg, Wa2, ba2, Wm3, bm3, h2, g, N);

    // ---- layer 3 ----
    hipMemsetAsync(agg, 0, (size_t)N * 52 * sizeof(float), stream);
    if (useBf)
        edge_mfma<32, 32, 2><<<EB, 256, 0, stream>>>(g, ebf, recs, Wb3, agg);
    else
        edge_fb<32, 32, 33><<<EB, 256, 0, stream>>>(g, efeats, recs, Wp3, agg);
    node_kernel<25, 28, 32, 32, 32, 0, 0><<<NB, 256, 0, stream>>>(
        h2, agg, Wa3, ba3, nullptr, nullptr, out, nullptr, N);
}